// Round 6
// baseline (408.599 us; speedup 1.0000x reference)
//
#include <hip/hip_runtime.h>
#include <cstdint>
#include <cstddef>

// Problem constants
#define BT     32768   // batch (titles)
#define NW     30      // words per title
#define VOCAB  32000
#define WD     300     // word dim
#define CH     400     // conv channels
#define AD     200     // attention dim

// Padded layouts
#define EMB_LD   320   // emb_bf16 [VOCAB][320]  (300 + pad)
#define E3_LDB   640   // E3 uint8 [VOCAB][640] bytes (600 + pad), biased +128
#define U_LD     928   // U bf16 [BT][928]       (900 + pad)
#define WCT_ROWS 512   // WcT bf16 [512][928]    (400 + pad rows)
#define EXPA_LD  32    // expa [BT][32]          (30 + pad)

#define TWO_LOG2E 2.8853900817779268f   // 2*log2(e): E3 holds 2s*log2e -> exp2 direct
#define QRANGE 14.0f                    // int8 scale range for E3 (~4 sigma; clips saturate tanh)
#define QSC  (127.0f / QRANGE)
#define QDEC (QRANGE / 127.0f)
#define QB3  (-384.0f * QDEC)           // 3-segment byte bias (each byte +128)

typedef __attribute__((ext_vector_type(8))) short bf16x8;
typedef __attribute__((ext_vector_type(4))) float f32x4;
typedef __attribute__((ext_vector_type(2))) float f32x2;

__device__ __forceinline__ float blo(unsigned int u) {
  union { unsigned int i; float f; } x; x.i = u << 16; return x.f;
}
__device__ __forceinline__ float bhi(unsigned int u) {
  union { unsigned int i; float f; } x; x.i = u & 0xffff0000u; return x.f;
}
__device__ __forceinline__ unsigned short f2bf(float f) {
  union { float f; unsigned int i; } x; x.f = f;
  unsigned int r = x.i + 0x7FFFu + ((x.i >> 16) & 1u);   // RNE
  return (unsigned short)(r >> 16);
}
__device__ __forceinline__ unsigned int pack2bf(float a, float b) {
  return (unsigned int)f2bf(a) | ((unsigned int)f2bf(b) << 16);
}
__device__ __forceinline__ float fexp2(float x) {
#if __has_builtin(__builtin_amdgcn_exp2f)
  return __builtin_amdgcn_exp2f(x);
#else
  float r; asm volatile("v_exp_f32 %0, %1" : "=v"(r) : "v"(x)); return r;
#endif
}
// single-op byte->float (v_cvt_f32_ubyteN), fallback to bfe+cvt
__device__ __forceinline__ float cvtub0(unsigned u) {
#if __has_builtin(__builtin_amdgcn_cvt_f32_ubyte0)
  return __builtin_amdgcn_cvt_f32_ubyte0(u);
#else
  return (float)(u & 0xffu);
#endif
}
__device__ __forceinline__ float cvtub1(unsigned u) {
#if __has_builtin(__builtin_amdgcn_cvt_f32_ubyte1)
  return __builtin_amdgcn_cvt_f32_ubyte1(u);
#else
  return (float)((u >> 8) & 0xffu);
#endif
}
__device__ __forceinline__ float cvtub2(unsigned u) {
#if __has_builtin(__builtin_amdgcn_cvt_f32_ubyte2)
  return __builtin_amdgcn_cvt_f32_ubyte2(u);
#else
  return (float)((u >> 16) & 0xffu);
#endif
}
__device__ __forceinline__ float cvtub3(unsigned u) {
#if __has_builtin(__builtin_amdgcn_cvt_f32_ubyte3)
  return __builtin_amdgcn_cvt_f32_ubyte3(u);
#else
  return (float)(u >> 24);
#endif
}
// packed f32 fma (v_pk_fma_f32 on gfx950)
__device__ __forceinline__ f32x2 pkfma(f32x2 a, f32x2 b, f32x2 c) {
#if __has_builtin(__builtin_elementwise_fma)
  return __builtin_elementwise_fma(a, b, c);
#else
  return a * b + c;
#endif
}

// ---------------------------------------------------------------------------
// Fused prep (write-major over MtT):
// block n<640: MtT[n][i] = bf16(2*log2e * sum_c conv_w[c,i,k]*v[c,d]),
//              n = k*200+d, zero for n>=600 or i>=300.
// block 640: bias2[d] = 2*log2e * (sum_c conv_b[c]*v[c,d] + vb[d])
// block 641: q2s[d] = -2*q[d]; qsum[0] = sum_d q[d]
// ---------------------------------------------------------------------------
__global__ void prep_MtT_bias(const float* __restrict__ conv_w,
                              const float* __restrict__ conv_b,
                              const float* __restrict__ v,
                              const float* __restrict__ vb,
                              const float* __restrict__ q,
                              unsigned short* __restrict__ MtT,
                              float* __restrict__ bias2,
                              float* __restrict__ q2s,
                              float* __restrict__ qsum) {
  int blk = blockIdx.x;      // 0..639 -> MtT row; 640 -> bias2; 641 -> q2s/qsum
  int i = threadIdx.x;       // 0..319
  if (blk < 640) {
    float val = 0.f;
    if (blk < 600 && i < WD) {
      int k = blk / AD, d = blk - k * AD;
      float acc = 0.f;
      #pragma unroll 4
      for (int c = 0; c < CH; ++c)
        acc += conv_w[(c * WD + i) * 3 + k] * v[c * AD + d];
      val = TWO_LOG2E * acc;
    }
    MtT[blk * EMB_LD + i] = f2bf(val);
  } else if (blk == 640) {
    if (i < AD) {
      float acc = vb[i];
      #pragma unroll 4
      for (int c = 0; c < CH; ++c)
        acc += conv_b[c] * v[c * AD + i];
      bias2[i] = TWO_LOG2E * acc;
    }
  } else {
    if (i < AD) q2s[i] = -2.0f * q[i];
    if (i == 0) {
      float s = 0.f;
      for (int j = 0; j < AD; ++j) s += q[j];
      qsum[0] = s;
    }
  }
}

// WcT[c][kk] = bf16(conv_w[c, i, k]), kk = k*300+i; zero-padded. [512][928]
__global__ void prep_WcT(const float* __restrict__ conv_w, unsigned short* __restrict__ WcT) {
  int c = blockIdx.x;    // 512
  for (int kk = threadIdx.x; kk < U_LD; kk += 256) {
    float val = 0.f;
    if (c < CH && kk < 900) {
      int k = kk / WD, i = kk - k * WD;
      val = conv_w[(c * WD + i) * 3 + k];
    }
    WcT[(size_t)c * U_LD + kk] = f2bf(val);
  }
}

// emb -> bf16, zero-padded cols. [VOCAB][320]
__global__ void prep_emb_bf16(const float* __restrict__ emb, unsigned short* __restrict__ embb) {
  int idx = blockIdx.x * 256 + threadIdx.x;
  if (idx >= VOCAB * EMB_LD) return;
  int r = idx / EMB_LD, c = idx - r * EMB_LD;
  embb[idx] = (c < WD) ? f2bf(emb[(size_t)r * WD + c]) : (unsigned short)0;
}

// ---------------------------------------------------------------------------
// bf16 MFMA GEMM: C[M,N] = A[M,K] @ Bt[N,K]^T. 128x128 tile, K-step 32.
// MODE 1: biased-uint8 store (quantize by QSC, +128), e3bias on cols [200,400).
// MODE 0: fp32 store with col<N guard + rank-1 bias_m[r]*bias_n[c].
// XCD-chunked bijective block swizzle (m204) for A-panel L2 locality.
// ---------------------------------------------------------------------------
template<int MODE>
__global__ __launch_bounds__(256) void gemm_mfma(
    const unsigned short* __restrict__ A, int lda,
    const unsigned short* __restrict__ Bt, int ldb,
    void* __restrict__ Cp, int ldc, int N, int K,
    const float* __restrict__ bias_m, const float* __restrict__ bias_n,
    const float* __restrict__ e3bias) {
  __shared__ unsigned short As[128][40];   // +8 pad
  __shared__ unsigned short Bs[128][40];
  int tid = threadIdx.x;
  int lane = tid & 63, wave = tid >> 6;

  // XCD-aware bijective swizzle: contiguous tile chunks per XCD.
  int gx = gridDim.x;
  int nwg = gx * (int)gridDim.y;
  int orig = blockIdx.y * gx + blockIdx.x;
  int xcd = orig & 7, qq = nwg >> 3, rr = nwg & 7;
  int wg = (xcd < rr ? xcd * (qq + 1) : rr * (qq + 1) + (xcd - rr) * qq) + (orig >> 3);
  int row0 = (wg / gx) * 128, col0 = (wg % gx) * 128;

  int wm = (wave & 1) * 64, wn = (wave >> 1) * 64;
  int lr = lane & 15, quad = lane >> 4;

  f32x4 acc[4][4];
  #pragma unroll
  for (int i = 0; i < 4; ++i)
    #pragma unroll
    for (int j = 0; j < 4; ++j) acc[i][j] = (f32x4){0.f, 0.f, 0.f, 0.f};

  int r0 = tid >> 2, ko0 = (tid & 3) * 8;
  int r1 = (tid + 256) >> 2, ko1 = ((tid + 256) & 3) * 8;

  for (int k0 = 0; k0 < K; k0 += 32) {
    float4 av0 = *(const float4*)(A + (size_t)(row0 + r0) * lda + k0 + ko0);
    float4 av1 = *(const float4*)(A + (size_t)(row0 + r1) * lda + k0 + ko1);
    float4 bv0 = *(const float4*)(Bt + (size_t)(col0 + r0) * ldb + k0 + ko0);
    float4 bv1 = *(const float4*)(Bt + (size_t)(col0 + r1) * ldb + k0 + ko1);
    __syncthreads();
    *(float4*)&As[r0][ko0] = av0;
    *(float4*)&As[r1][ko1] = av1;
    *(float4*)&Bs[r0][ko0] = bv0;
    *(float4*)&Bs[r1][ko1] = bv1;
    __syncthreads();

    bf16x8 af[4], bfr[4];
    #pragma unroll
    for (int mi = 0; mi < 4; ++mi)
      af[mi] = *(const bf16x8*)&As[wm + mi * 16 + lr][quad * 8];
    #pragma unroll
    for (int ni = 0; ni < 4; ++ni)
      bfr[ni] = *(const bf16x8*)&Bs[wn + ni * 16 + lr][quad * 8];
    #pragma unroll
    for (int mi = 0; mi < 4; ++mi)
      #pragma unroll
      for (int ni = 0; ni < 4; ++ni)
        acc[mi][ni] = __builtin_amdgcn_mfma_f32_16x16x32_bf16(
            af[mi], bfr[ni], acc[mi][ni], 0, 0, 0);
  }

  // Epilogue. C/D layout: col = lane&15, row = quad*4 + reg.
  if (MODE == 1) {
    unsigned char* C = (unsigned char*)Cp;
    #pragma unroll
    for (int mi = 0; mi < 4; ++mi)
      #pragma unroll
      for (int ni = 0; ni < 4; ++ni) {
        int c = col0 + wn + ni * 16 + lr;
        float cb = (e3bias && c >= 200 && c < 400) ? e3bias[c - 200] : 0.f;
        #pragma unroll
        for (int reg = 0; reg < 4; ++reg) {
          int r = row0 + wm + mi * 16 + quad * 4 + reg;
          float x = (acc[mi][ni][reg] + cb) * QSC;
          int qi = (int)rintf(x);
          qi = qi > 127 ? 127 : (qi < -127 ? -127 : qi);
          C[(size_t)r * ldc + c] = (unsigned char)(qi + 128);
        }
      }
  } else {
    float* C = (float*)Cp;
    #pragma unroll
    for (int mi = 0; mi < 4; ++mi)
      #pragma unroll
      for (int ni = 0; ni < 4; ++ni) {
        int c = col0 + wn + ni * 16 + lr;
        if (c < N) {
          float bn = bias_n[c];
          #pragma unroll
          for (int reg = 0; reg < 4; ++reg) {
            int r = row0 + wm + mi * 16 + quad * 4 + reg;
            C[(size_t)r * ldc + c] = acc[mi][ni][reg] + bias_m[r] * bn;
          }
        }
      }
  }
}

// ---------------------------------------------------------------------------
// Scores, TITLE-per-wave, ROLLING-WINDOW over tokens, biased-uint8 E3.
// R6 VALU diet (kernel was 100% VALU-issue-bound at 223 cyc/iter):
//  - readlane -> SGPR row base: load addressing moves to SALU; the three
//    segment loads share one scalar base + v_d0 offset + imm 0/200/400.
//  - v_cvt_f32_ubyteN builtins: guaranteed 1-op byte->float.
//  - float2 window + v_pk_add_f32 / v_pk_fma_f32 for the arg chains.
//  - factored sigmoid-pair rational: q0*s0+q1*s1 = [q0 f1 + q1 f0]/(f0 f1),
//    f = exp2(arg)+1. Identical algebra, 2 rcp per 4 dims.
// ---------------------------------------------------------------------------
__global__ __launch_bounds__(256) void scores_kernel(
    const int* __restrict__ tok, const unsigned char* __restrict__ E3,
    const float* __restrict__ q2s, const float* __restrict__ qsum,
    float* __restrict__ expa) {
  __shared__ float qs[AD];
  __shared__ __align__(16) float red[4][NW][36];   // stride 36 floats = 144B (16B aligned)
  int tid = threadIdx.x;
  if (tid < AD) qs[tid] = q2s[tid];
  __syncthreads();
  int wave = tid >> 6, lane = tid & 63;
  int b = blockIdx.x * 4 + wave;
  int tk = tok[b * NW + ((lane < NW) ? lane : 0)];
  int d0 = (lane < 50) ? lane * 4 : 0;
  float4 qv = make_float4(0.f, 0.f, 0.f, 0.f);
  if (lane < 50) qv = *(const float4*)&qs[d0];   // lanes >=50 contribute 0
  float Qsum = qsum[0];
  float* myred = &red[wave][0][lane >> 1];       // word stride = 36 floats

  const f32x2 qdecv = {QDEC, QDEC};
  const f32x2 qb3v  = {QB3, QB3};

  // Prefetch row tok[0] via SGPR base.
  int t0r = __builtin_amdgcn_readlane(tk, 0);
  const unsigned char* r0p = E3 + (size_t)(unsigned)t0r * E3_LDB;
  unsigned int a0 = *(const unsigned int*)(r0p + d0);          // seg0 -> s[1]
  unsigned int a1 = *(const unsigned int*)(r0p + d0 + 200);    // seg1 -> s[0]
  unsigned int a2 = *(const unsigned int*)(r0p + d0 + 400);    // seg2 -> s[-1] (dropped)

  // fp32 window of biased bytes (packed pairs); virtual seg0(tok[-1]) = 128.
  f32x2 p01 = {0.f, 0.f}, p23 = {0.f, 0.f};
  f32x2 q01 = {128.f, 128.f}, q23 = {128.f, 128.f};

  #pragma unroll
  for (int m = 0; m < NW; ++m) {
    unsigned int u0 = a0, u1 = a1, u2 = a2;
    if (m + 1 < NW) {   // prefetch next token's row (SGPR base, indep of below)
      int tn = __builtin_amdgcn_readlane(tk, m + 1);
      const unsigned char* rp = E3 + (size_t)(unsigned)tn * E3_LDB;
      a0 = *(const unsigned int*)(rp + d0);
      a1 = *(const unsigned int*)(rp + d0 + 200);
      a2 = *(const unsigned int*)(rp + d0 + 400);
    }
    if (m > 0) {
      // complete s[m-1] with seg2 of current row; sigmoid-pair; park.
      f32x2 c01 = { cvtub0(u2), cvtub1(u2) };
      f32x2 c23 = { cvtub2(u2), cvtub3(u2) };
      f32x2 g01 = pkfma(p01 + c01, qdecv, qb3v);
      f32x2 g23 = pkfma(p23 + c23, qdecv, qb3v);
      float f0 = fexp2(g01.x) + 1.0f;
      float f1 = fexp2(g01.y) + 1.0f;
      float f2 = fexp2(g23.x) + 1.0f;
      float f3 = fexp2(g23.y) + 1.0f;
      float n01 = fmaf(qv.y, f0, qv.x * f1);
      float n23 = fmaf(qv.w, f2, qv.z * f3);
      float acc = n01 * __builtin_amdgcn_rcpf(f0 * f1);
      acc = fmaf(n23, __builtin_amdgcn_rcpf(f2 * f3), acc);
      acc += __shfl_xor(acc, 1, 64);          // lanes 2k,2k+1 now equal
      myred[(m - 1) * 36] = acc;              // benign same-value dual write
    }
    // advance window: P' = Q + seg1(tok[m]); Q' = seg0(tok[m])
    f32x2 b01 = { cvtub0(u1), cvtub1(u1) };
    f32x2 b23 = { cvtub2(u1), cvtub3(u1) };
    p01 = q01 + b01; p23 = q23 + b23;
    q01 = (f32x2){ cvtub0(u0), cvtub1(u0) };
    q23 = (f32x2){ cvtub2(u0), cvtub3(u0) };
  }
  { // epilogue: s[29] complete; missing seg2 -> bias 128
    const f32x2 c128 = {128.f, 128.f};
    f32x2 g01 = pkfma(p01 + c128, qdecv, qb3v);
    f32x2 g23 = pkfma(p23 + c128, qdecv, qb3v);
    float f0 = fexp2(g01.x) + 1.0f;
    float f1 = fexp2(g01.y) + 1.0f;
    float f2 = fexp2(g23.x) + 1.0f;
    float f3 = fexp2(g23.y) + 1.0f;
    float n01 = fmaf(qv.y, f0, qv.x * f1);
    float n23 = fmaf(qv.w, f2, qv.z * f3);
    float acc = n01 * __builtin_amdgcn_rcpf(f0 * f1);
    acc = fmaf(n23, __builtin_amdgcn_rcpf(f2 * f3), acc);
    acc += __shfl_xor(acc, 1, 64);
    myred[(NW - 1) * 36] = acc;
  }
  __syncthreads();
  // Transpose-reduce: word n's 32 partials; lane n sums j=0..15, lane n+32
  // sums j=16..31; xor-32 combines. Lanes with n>=30 are dummies.
  int n = lane & 31; if (n >= NW) n = 0;
  int half = lane >> 5;
  const float4* rp4 = (const float4*)&red[wave][n][half * 16];
  float4 s4 = rp4[0];
  #pragma unroll
  for (int j = 1; j < 4; ++j) {
    float4 vv = rp4[j];
    s4.x += vv.x; s4.y += vv.y; s4.z += vv.z; s4.w += vv.w;
  }
  float tot = (s4.x + s4.y) + (s4.z + s4.w);
  tot += __shfl_xor(tot, 32, 64);
  // |score| <= sum|q| ~ 16 -> exp safe in fp32; softmax needs no max-shift.
  float e = __expf(Qsum + tot);
  if (lane < NW) expa[(size_t)b * EXPA_LD + lane] = e;
}

// ---------------------------------------------------------------------------
// Softmax-over-batch denominators, stage 1: 128 blocks x 256 titles each.
// part[n][blk] = sum over block's titles of expa[b][n].
// ---------------------------------------------------------------------------
__global__ __launch_bounds__(256) void softmax_part(const float* __restrict__ expa,
                                                    float* __restrict__ part) {
  __shared__ float P[256][33];
  int tid = threadIdx.x;
  const float* row = expa + (size_t)(blockIdx.x * 256 + tid) * EXPA_LD;
  #pragma unroll
  for (int j = 0; j < 7; ++j) {
    float4 vv = *(const float4*)(row + j * 4);
    P[tid][j * 4] = vv.x; P[tid][j * 4 + 1] = vv.y;
    P[tid][j * 4 + 2] = vv.z; P[tid][j * 4 + 3] = vv.w;
  }
  P[tid][28] = row[28]; P[tid][29] = row[29];
  __syncthreads();
  int wave = tid >> 6, lane = tid & 63;
  for (int n = wave * 8; n < wave * 8 + 8 && n < NW; ++n) {
    float s = P[lane * 4][n] + P[lane * 4 + 1][n] + P[lane * 4 + 2][n] + P[lane * 4 + 3][n];
    #pragma unroll
    for (int off = 32; off > 0; off >>= 1) s += __shfl_down(s, off, 64);
    if (lane == 0) part[n * 128 + blockIdx.x] = s;
  }
}

// Stage 2: rinv[n] = 1 / sum_blk part[n][blk]
__global__ void softmax_fin(const float* __restrict__ part, float* __restrict__ rinv) {
  int n = blockIdx.x;          // 30
  int lane = threadIdx.x;      // 64
  float s = part[n * 128 + lane] + part[n * 128 + 64 + lane];
  #pragma unroll
  for (int off = 32; off > 0; off >>= 1) s += __shfl_down(s, off, 64);
  if (lane == 0) rinv[n] = 1.0f / s;
}

// ---------------------------------------------------------------------------
// U[b, k*300+i] = sum_m alpha[b, m-k+1] * emb[tok[b,m], i]  -> bf16, stride 928
// Salpha[b] = sum_n alpha[b,n].  alpha = expa * rinv.
// Prefetch-all-30 (R5) + packed-f32 fma pairs (R6).
// ---------------------------------------------------------------------------
__global__ __launch_bounds__(192) void build_U(
    const int* __restrict__ tok, const unsigned short* __restrict__ embb,
    const float* __restrict__ expa, const float* __restrict__ rinv,
    unsigned short* __restrict__ U, float* __restrict__ Salpha) {
  int b = blockIdx.x;
  int tid = threadIdx.x;
  __shared__ float alpha[NW];
  __shared__ int ltok[NW];
  if (tid < NW) {
    ltok[tid] = tok[b * NW + tid];
    alpha[tid] = expa[(size_t)b * EXPA_LD + tid] * rinv[tid];
  }
  __syncthreads();
  if (tid == 0) {
    float s = 0.f;
    #pragma unroll
    for (int n = 0; n < NW; ++n) s += alpha[n];
    Salpha[b] = s;
  }
  unsigned short* Ub = U + (size_t)b * U_LD;
  if (tid < 150) {
    // Issue all 30 gathers (independent, fully unrolled -> 30 loads in flight)
    unsigned int uv[NW];
    #pragma unroll
    for (int m = 0; m < NW; ++m)
      uv[m] = *(const unsigned int*)(embb + (size_t)ltok[m] * EMB_LD + 2 * tid);
    // Broadcast alphas to registers (uniform ds_read, no conflicts)
    float al[NW];
    #pragma unroll
    for (int m = 0; m < NW; ++m) al[m] = alpha[m];

    f32x2 A0 = {0.f, 0.f}, A1 = {0.f, 0.f}, A2 = {0.f, 0.f};
    #pragma unroll
    for (int m = 0; m < NW; ++m) {
      f32x2 xy = { blo(uv[m]), bhi(uv[m]) };
      if (m + 1 < NW) {
        f32x2 wv = { al[m + 1], al[m + 1] };
        A0 = pkfma(wv, xy, A0);
      }
      {
        f32x2 wv = { al[m], al[m] };
        A1 = pkfma(wv, xy, A1);
      }
      if (m >= 1) {
        f32x2 wv = { al[m - 1], al[m - 1] };
        A2 = pkfma(wv, xy, A2);
      }
    }
    *(unsigned int*)(Ub + 2 * tid)       = pack2bf(A0.x, A0.y);
    *(unsigned int*)(Ub + 300 + 2 * tid) = pack2bf(A1.x, A1.y);
    *(unsigned int*)(Ub + 600 + 2 * tid) = pack2bf(A2.x, A2.y);
  } else if (tid < 164) {
    *(unsigned int*)(Ub + 900 + 2 * (tid - 150)) = 0u;   // zero pad 900..927
  }
}

// ---------------------------------------------------------------------------
extern "C" void kernel_launch(void* const* d_in, const int* in_sizes, int n_in,
                              void* d_out, int out_size, void* d_ws, size_t ws_size,
                              hipStream_t stream) {
  const int*   tok    = (const int*)d_in[0];
  const float* emb    = (const float*)d_in[1];
  const float* conv_w = (const float*)d_in[2];
  const float* conv_b = (const float*)d_in[3];
  const float* v      = (const float*)d_in[4];
  const float* vb     = (const float*)d_in[5];
  const float* q      = (const float*)d_in[6];
  float* out = (float*)d_out;

  // Workspace layout (byte offsets). Total ~87.8 MB.
  char* wb = (char*)d_ws;
  float* bias2           = (float*)(wb + 0);          // 200 f32
  float* rinv            = (float*)(wb + 4096);       // 30 f32
  float* part            = (float*)(wb + 8192);       // 30*128 f32 -> 23552
  float* q2s             = (float*)(wb + 23552);      // 200 f32
  float* qsum            = (float*)(wb + 24448);      // 1 f32
  float* Salpha          = (float*)(wb + 24576);      // 32768 f32 -> 155648
  float* expa            = (float*)(wb + 155648);     // 32768*32 f32 -> 4349952
  unsigned short* embb   = (unsigned short*)(wb + 5070848);   // 20.48MB -> 25550848
  unsigned short* MtT    = (unsigned short*)(wb + 25550848);  // 409600 -> 25960448
  unsigned short* WcT    = (unsigned short*)(wb + 25960448);  // 950272 -> 26910720
  unsigned short* big    = (unsigned short*)(wb + 26910720);  // E3 u8 (20.5MB) / U (60.8MB)
  unsigned char* E3 = (unsigned char*)big;
  unsigned short* U = big;   // E3 dead after scores_kernel

  // 1. Prep
  hipLaunchKernelGGL(prep_MtT_bias, dim3(642), dim3(320), 0, stream,
                     conv_w, conv_b, v, vb, q, MtT, bias2, q2s, qsum);
  hipLaunchKernelGGL(prep_WcT, dim3(WCT_ROWS), dim3(256), 0, stream, conv_w, WcT);
  hipLaunchKernelGGL(prep_emb_bf16, dim3((VOCAB * EMB_LD) / 256), dim3(256), 0, stream,
                     emb, embb);
  // 2. E3[32000,640]u8 = quant(embb @ MtT^T)+128, bias2 folded into cols [200,400)
  hipLaunchKernelGGL((gemm_mfma<1>), dim3(E3_LDB / 128, VOCAB / 128), dim3(256), 0, stream,
                     embb, EMB_LD, MtT, EMB_LD, (void*)E3, E3_LDB, E3_LDB, EMB_LD,
                     (const float*)nullptr, (const float*)nullptr, bias2);
  // 3. exp(scores) -> expa[b][n]  (rolling-window uint8 gather, LDS reduce)
  hipLaunchKernelGGL(scores_kernel, dim3(BT / 4), dim3(256), 0, stream,
                     tok, E3, q2s, qsum, expa);
  // 4. Softmax denominators (2-stage, deterministic)
  hipLaunchKernelGGL(softmax_part, dim3(128), dim3(256), 0, stream, expa, part);
  hipLaunchKernelGGL(softmax_fin, dim3(NW), dim3(64), 0, stream, part, rinv);
  // 5. U[32768,928]bf16 + Salpha
  hipLaunchKernelGGL(build_U, dim3(BT), dim3(192), 0, stream,
                     tok, embb, expa, rinv, U, Salpha);
  // 6. out[32768,400]f32 = U @ WcT^T + Salpha ⊗ conv_b
  hipLaunchKernelGGL((gemm_mfma<0>), dim3(WCT_ROWS / 128, BT / 128), dim3(256), 0, stream,
                     U, U_LD, WcT, U_LD, (void*)out, CH, CH, U_LD,
                     Salpha, conv_b, (const float*)nullptr);
}

// Round 7
// 406.755 us; speedup vs baseline: 1.0045x; 1.0045x over previous
//
#include <hip/hip_runtime.h>
#include <cstdint>
#include <cstddef>

// Problem constants
#define BT     32768   // batch (titles)
#define NW     30      // words per title
#define VOCAB  32000
#define WD     300     // word dim
#define CH     400     // conv channels
#define AD     200     // attention dim

// Padded layouts
#define EMB_LD   320   // emb_bf16 [VOCAB][320]  (300 + pad)
#define E3_LDB   640   // E3 uint8 [VOCAB][640] bytes (600 + pad), biased +128
#define U_LD     928   // U bf16 [BT][928]       (900 + pad)
#define WCT_ROWS 512   // WcT bf16 [512][928]    (400 + pad rows)
#define EXPA_LD  32    // expa [BT][32]          (30 + pad)

#define TWO_LOG2E 2.8853900817779268f   // 2*log2(e): E3 holds 2s*log2e -> exp2 direct
#define QRANGE 14.0f                    // int8 scale range for E3 (~4 sigma; clips saturate tanh)
#define QSC  (127.0f / QRANGE)
#define QDEC (QRANGE / 127.0f)
#define QB3  (-384.0f * QDEC)           // 3-segment byte bias (each byte +128)

typedef __attribute__((ext_vector_type(8))) short bf16x8;
typedef __attribute__((ext_vector_type(4))) float f32x4;

__device__ __forceinline__ float blo(unsigned int u) {
  union { unsigned int i; float f; } x; x.i = u << 16; return x.f;
}
__device__ __forceinline__ float bhi(unsigned int u) {
  union { unsigned int i; float f; } x; x.i = u & 0xffff0000u; return x.f;
}
__device__ __forceinline__ unsigned short f2bf(float f) {
  union { float f; unsigned int i; } x; x.f = f;
  unsigned int r = x.i + 0x7FFFu + ((x.i >> 16) & 1u);   // RNE
  return (unsigned short)(r >> 16);
}
__device__ __forceinline__ unsigned int pack2bf(float a, float b) {
  return (unsigned int)f2bf(a) | ((unsigned int)f2bf(b) << 16);
}
__device__ __forceinline__ float fexp2(float x) {
#if __has_builtin(__builtin_amdgcn_exp2f)
  return __builtin_amdgcn_exp2f(x);
#else
  float r; asm volatile("v_exp_f32 %0, %1" : "=v"(r) : "v"(x)); return r;
#endif
}
// unsigned byte j of packed u, as float (compiler emits v_cvt_f32_ubyteN)
#define UBF(u, j) ((float)(((u) >> (8 * (j))) & 0xffu))

// async global->LDS, 16B per lane (global_load_lds_dwordx4)
__device__ __forceinline__ void gload16(const void* g, void* l) {
  __builtin_amdgcn_global_load_lds(
      (const __attribute__((address_space(1))) void*)g,
      (__attribute__((address_space(3))) void*)l, 16, 0, 0);
}

// ---------------------------------------------------------------------------
// Fused prep (write-major over MtT):
// block n<640: MtT[n][i] = bf16(2*log2e * sum_c conv_w[c,i,k]*v[c,d]),
//              n = k*200+d, zero for n>=600 or i>=300.
// block 640: bias2[d] = 2*log2e * (sum_c conv_b[c]*v[c,d] + vb[d])
// block 641: q2s[d] = -2*q[d]; qsum[0] = sum_d q[d]
// ---------------------------------------------------------------------------
__global__ void prep_MtT_bias(const float* __restrict__ conv_w,
                              const float* __restrict__ conv_b,
                              const float* __restrict__ v,
                              const float* __restrict__ vb,
                              const float* __restrict__ q,
                              unsigned short* __restrict__ MtT,
                              float* __restrict__ bias2,
                              float* __restrict__ q2s,
                              float* __restrict__ qsum) {
  int blk = blockIdx.x;      // 0..639 -> MtT row; 640 -> bias2; 641 -> q2s/qsum
  int i = threadIdx.x;       // 0..319
  if (blk < 640) {
    float val = 0.f;
    if (blk < 600 && i < WD) {
      int k = blk / AD, d = blk - k * AD;
      float acc = 0.f;
      #pragma unroll 4
      for (int c = 0; c < CH; ++c)
        acc += conv_w[(c * WD + i) * 3 + k] * v[c * AD + d];
      val = TWO_LOG2E * acc;
    }
    MtT[blk * EMB_LD + i] = f2bf(val);
  } else if (blk == 640) {
    if (i < AD) {
      float acc = vb[i];
      #pragma unroll 4
      for (int c = 0; c < CH; ++c)
        acc += conv_b[c] * v[c * AD + i];
      bias2[i] = TWO_LOG2E * acc;
    }
  } else {
    if (i < AD) q2s[i] = -2.0f * q[i];
    if (i == 0) {
      float s = 0.f;
      for (int j = 0; j < AD; ++j) s += q[j];
      qsum[0] = s;
    }
  }
}

// WcT[c][kk] = bf16(conv_w[c, i, k]), kk = k*300+i; zero-padded. [512][928]
__global__ void prep_WcT(const float* __restrict__ conv_w, unsigned short* __restrict__ WcT) {
  int c = blockIdx.x;    // 512
  for (int kk = threadIdx.x; kk < U_LD; kk += 256) {
    float val = 0.f;
    if (c < CH && kk < 900) {
      int k = kk / WD, i = kk - k * WD;
      val = conv_w[(c * WD + i) * 3 + k];
    }
    WcT[(size_t)c * U_LD + kk] = f2bf(val);
  }
}

// emb -> bf16, zero-padded cols. [VOCAB][320]
__global__ void prep_emb_bf16(const float* __restrict__ emb, unsigned short* __restrict__ embb) {
  int idx = blockIdx.x * 256 + threadIdx.x;
  if (idx >= VOCAB * EMB_LD) return;
  int r = idx / EMB_LD, c = idx - r * EMB_LD;
  embb[idx] = (c < WD) ? f2bf(emb[(size_t)r * WD + c]) : (unsigned short)0;
}

// ---------------------------------------------------------------------------
// bf16 MFMA GEMM: C[M,N] = A[M,K] @ Bt[N,K]^T. 128x128 tile, K-step 32.
// R7: m97-style staging -- global_load_lds width-16 direct to LINEAR LDS
// [128][32] (no pad; gload_lds needs contiguous lane-order dest). Kills the
// per-iter VGPR round-trip + staging address VALU (measured ladder m93->m97:
// 517->874 TF). Thread t's 16B lands at LDS byte t*16 = row t/4, col (t%4)*8,
// identical mapping to the old reg-staged version.
// MODE 1: biased-uint8 store (quantize by QSC, +128), e3bias on cols [200,400).
// MODE 0: fp32 store with col<N guard + rank-1 bias_m[r]*bias_n[c].
// XCD-chunked bijective block swizzle (m204) for A-panel L2 locality.
// ---------------------------------------------------------------------------
template<int MODE>
__global__ __launch_bounds__(256) void gemm_mfma(
    const unsigned short* __restrict__ A, int lda,
    const unsigned short* __restrict__ Bt, int ldb,
    void* __restrict__ Cp, int ldc, int N, int K,
    const float* __restrict__ bias_m, const float* __restrict__ bias_n,
    const float* __restrict__ e3bias) {
  __shared__ unsigned short As[128][32];   // linear, 8KB
  __shared__ unsigned short Bs[128][32];
  int tid = threadIdx.x;
  int lane = tid & 63, wave = tid >> 6;

  // XCD-aware bijective swizzle: contiguous tile chunks per XCD.
  int gx = gridDim.x;
  int nwg = gx * (int)gridDim.y;
  int orig = blockIdx.y * gx + blockIdx.x;
  int xcd = orig & 7, qq = nwg >> 3, rr = nwg & 7;
  int wg = (xcd < rr ? xcd * (qq + 1) : rr * (qq + 1) + (xcd - rr) * qq) + (orig >> 3);
  int row0 = (wg / gx) * 128, col0 = (wg % gx) * 128;

  int wm = (wave & 1) * 64, wn = (wave >> 1) * 64;
  int lr = lane & 15, quad = lane >> 4;

  f32x4 acc[4][4];
  #pragma unroll
  for (int i = 0; i < 4; ++i)
    #pragma unroll
    for (int j = 0; j < 4; ++j) acc[i][j] = (f32x4){0.f, 0.f, 0.f, 0.f};

  int r0 = tid >> 2, ko0 = (tid & 3) * 8;   // issue0: rows 0..63
  int r1 = r0 + 64;                          // issue1: rows 64..127, same ko

  char* AsB = (char*)As;
  char* BsB = (char*)Bs;
  char* dA0 = AsB + tid * 16;
  char* dA1 = AsB + 4096 + tid * 16;
  char* dB0 = BsB + tid * 16;
  char* dB1 = BsB + 4096 + tid * 16;
  const unsigned short* gA0 = A + (size_t)(row0 + r0) * lda + ko0;
  const unsigned short* gA1 = A + (size_t)(row0 + r1) * lda + ko0;
  const unsigned short* gB0 = Bt + (size_t)(col0 + r0) * ldb + ko0;
  const unsigned short* gB1 = Bt + (size_t)(col0 + r1) * ldb + ko0;

  for (int k0 = 0; k0 < K; k0 += 32) {
    __syncthreads();                  // all waves done reading previous tile
    gload16(gA0 + k0, dA0);
    gload16(gA1 + k0, dA1);
    gload16(gB0 + k0, dB0);
    gload16(gB1 + k0, dB1);
    __syncthreads();                  // drains vmcnt(0): tile resident

    bf16x8 af[4], bfr[4];
    #pragma unroll
    for (int mi = 0; mi < 4; ++mi)
      af[mi] = *(const bf16x8*)(AsB + (wm + mi * 16 + lr) * 64 + quad * 16);
    #pragma unroll
    for (int ni = 0; ni < 4; ++ni)
      bfr[ni] = *(const bf16x8*)(BsB + (wn + ni * 16 + lr) * 64 + quad * 16);
    #pragma unroll
    for (int mi = 0; mi < 4; ++mi)
      #pragma unroll
      for (int ni = 0; ni < 4; ++ni)
        acc[mi][ni] = __builtin_amdgcn_mfma_f32_16x16x32_bf16(
            af[mi], bfr[ni], acc[mi][ni], 0, 0, 0);
  }

  // Epilogue. C/D layout: col = lane&15, row = quad*4 + reg.
  if (MODE == 1) {
    unsigned char* C = (unsigned char*)Cp;
    #pragma unroll
    for (int mi = 0; mi < 4; ++mi)
      #pragma unroll
      for (int ni = 0; ni < 4; ++ni) {
        int c = col0 + wn + ni * 16 + lr;
        float cb = (e3bias && c >= 200 && c < 400) ? e3bias[c - 200] : 0.f;
        #pragma unroll
        for (int reg = 0; reg < 4; ++reg) {
          int r = row0 + wm + mi * 16 + quad * 4 + reg;
          float x = (acc[mi][ni][reg] + cb) * QSC;
          int qi = (int)rintf(x);
          qi = qi > 127 ? 127 : (qi < -127 ? -127 : qi);
          C[(size_t)r * ldc + c] = (unsigned char)(qi + 128);
        }
      }
  } else {
    float* C = (float*)Cp;
    #pragma unroll
    for (int mi = 0; mi < 4; ++mi)
      #pragma unroll
      for (int ni = 0; ni < 4; ++ni) {
        int c = col0 + wn + ni * 16 + lr;
        if (c < N) {
          float bn = bias_n[c];
          #pragma unroll
          for (int reg = 0; reg < 4; ++reg) {
            int r = row0 + wm + mi * 16 + quad * 4 + reg;
            C[(size_t)r * ldc + c] = acc[mi][ni][reg] + bias_m[r] * bn;
          }
        }
      }
  }
}

// ---------------------------------------------------------------------------
// Scores, TITLE-per-wave, ROLLING-WINDOW over tokens, biased-uint8 E3.
// (reverted verbatim to the R5 version: 89.4us, VALUBusy ~100%)
// ---------------------------------------------------------------------------
__global__ __launch_bounds__(256) void scores_kernel(
    const int* __restrict__ tok, const unsigned char* __restrict__ E3,
    const float* __restrict__ q2s, const float* __restrict__ qsum,
    float* __restrict__ expa) {
  __shared__ float qs[AD];
  __shared__ __align__(16) float red[4][NW][36];   // stride 36 floats = 144B (16B aligned)
  int tid = threadIdx.x;
  if (tid < AD) qs[tid] = q2s[tid];
  __syncthreads();
  int wave = tid >> 6, lane = tid & 63;
  int b = blockIdx.x * 4 + wave;
  int tk = tok[b * NW + ((lane < NW) ? lane : 0)];
  int d0 = (lane < 50) ? lane * 4 : 0;
  float4 qv = make_float4(0.f, 0.f, 0.f, 0.f);
  if (lane < 50) qv = *(const float4*)&qs[d0];   // lanes >=50 contribute 0
  float s01 = qv.x + qv.y, s23 = qv.z + qv.w;
  float Qsum = qsum[0];
  float* myred = &red[wave][0][lane >> 1];       // word stride = 36 floats

  // Prefetch row tok[0]: three 4B segment loads off one base.
  int t0r = __shfl(tk, 0, 64);
  const unsigned char* r0p = E3 + (size_t)(unsigned)t0r * E3_LDB + d0;
  unsigned int a0 = *(const unsigned int*)(r0p);          // seg0 -> s[1]
  unsigned int a1 = *(const unsigned int*)(r0p + 200);    // seg1 -> s[0]
  unsigned int a2 = *(const unsigned int*)(r0p + 400);    // seg2 -> s[-1] (dropped)

  // fp32 window of biased bytes; virtual seg0(tok[-1]) = bias 128.
  float P0 = 0.f, P1 = 0.f, P2 = 0.f, P3 = 0.f;
  float Q0 = 128.f, Q1 = 128.f, Q2 = 128.f, Q3 = 128.f;

  #pragma unroll
  for (int m = 0; m < NW; ++m) {
    unsigned int u0 = a0, u1 = a1, u2 = a2;
    if (m + 1 < NW) {   // prefetch next token's row (independent of below)
      int tn = __shfl(tk, m + 1, 64);
      const unsigned char* rp = E3 + (size_t)(unsigned)tn * E3_LDB + d0;
      a0 = *(const unsigned int*)(rp);
      a1 = *(const unsigned int*)(rp + 200);
      a2 = *(const unsigned int*)(rp + 400);
    }
    if (m > 0) {
      // complete s[m-1] with seg2 of current row; sigmoid; pair-park.
      float e0 = fexp2(fmaf(P0 + UBF(u2, 0), QDEC, QB3));
      float e1 = fexp2(fmaf(P1 + UBF(u2, 1), QDEC, QB3));
      float e2 = fexp2(fmaf(P2 + UBF(u2, 2), QDEC, QB3));
      float e3 = fexp2(fmaf(P3 + UBF(u2, 3), QDEC, QB3));
      float n01 = fmaf(qv.x, e1, s01); n01 = fmaf(qv.y, e0, n01);
      float n23 = fmaf(qv.z, e3, s23); n23 = fmaf(qv.w, e2, n23);
      float d01 = fmaf(e0, e1, (e0 + e1) + 1.0f);
      float d23 = fmaf(e2, e3, (e2 + e3) + 1.0f);
      float acc = n01 * __builtin_amdgcn_rcpf(d01);
      acc = fmaf(n23, __builtin_amdgcn_rcpf(d23), acc);
      acc += __shfl_xor(acc, 1, 64);          // lanes 2k,2k+1 now equal
      myred[(m - 1) * 36] = acc;              // benign same-value dual write
    }
    // advance window: P' = Q + seg1(tok[m]); Q' = seg0(tok[m])
    P0 = Q0 + UBF(u1, 0); P1 = Q1 + UBF(u1, 1);
    P2 = Q2 + UBF(u1, 2); P3 = Q3 + UBF(u1, 3);
    Q0 = UBF(u0, 0); Q1 = UBF(u0, 1);
    Q2 = UBF(u0, 2); Q3 = UBF(u0, 3);
  }
  { // epilogue: s[29] complete; missing seg2 -> bias 128
    float e0 = fexp2(fmaf(P0 + 128.f, QDEC, QB3));
    float e1 = fexp2(fmaf(P1 + 128.f, QDEC, QB3));
    float e2 = fexp2(fmaf(P2 + 128.f, QDEC, QB3));
    float e3 = fexp2(fmaf(P3 + 128.f, QDEC, QB3));
    float n01 = fmaf(qv.x, e1, s01); n01 = fmaf(qv.y, e0, n01);
    float n23 = fmaf(qv.z, e3, s23); n23 = fmaf(qv.w, e2, n23);
    float d01 = fmaf(e0, e1, (e0 + e1) + 1.0f);
    float d23 = fmaf(e2, e3, (e2 + e3) + 1.0f);
    float acc = n01 * __builtin_amdgcn_rcpf(d01);
    acc = fmaf(n23, __builtin_amdgcn_rcpf(d23), acc);
    acc += __shfl_xor(acc, 1, 64);
    myred[(NW - 1) * 36] = acc;
  }
  __syncthreads();
  // Transpose-reduce: word n's 32 partials; lane n sums j=0..15, lane n+32
  // sums j=16..31; xor-32 combines. Lanes with n>=30 are dummies.
  int n = lane & 31; if (n >= NW) n = 0;
  int half = lane >> 5;
  const float4* rp4 = (const float4*)&red[wave][n][half * 16];
  float4 s4 = rp4[0];
  #pragma unroll
  for (int j = 1; j < 4; ++j) {
    float4 vv = rp4[j];
    s4.x += vv.x; s4.y += vv.y; s4.z += vv.z; s4.w += vv.w;
  }
  float tot = (s4.x + s4.y) + (s4.z + s4.w);
  tot += __shfl_xor(tot, 32, 64);
  // |score| <= sum|q| ~ 16 -> exp safe in fp32; softmax needs no max-shift.
  float e = __expf(Qsum + tot);
  if (lane < NW) expa[(size_t)b * EXPA_LD + lane] = e;
}

// ---------------------------------------------------------------------------
// Softmax-over-batch denominators, stage 1: 128 blocks x 256 titles each.
// part[n][blk] = sum over block's titles of expa[b][n].
// ---------------------------------------------------------------------------
__global__ __launch_bounds__(256) void softmax_part(const float* __restrict__ expa,
                                                    float* __restrict__ part) {
  __shared__ float P[256][33];
  int tid = threadIdx.x;
  const float* row = expa + (size_t)(blockIdx.x * 256 + tid) * EXPA_LD;
  #pragma unroll
  for (int j = 0; j < 7; ++j) {
    float4 vv = *(const float4*)(row + j * 4);
    P[tid][j * 4] = vv.x; P[tid][j * 4 + 1] = vv.y;
    P[tid][j * 4 + 2] = vv.z; P[tid][j * 4 + 3] = vv.w;
  }
  P[tid][28] = row[28]; P[tid][29] = row[29];
  __syncthreads();
  int wave = tid >> 6, lane = tid & 63;
  for (int n = wave * 8; n < wave * 8 + 8 && n < NW; ++n) {
    float s = P[lane * 4][n] + P[lane * 4 + 1][n] + P[lane * 4 + 2][n] + P[lane * 4 + 3][n];
    #pragma unroll
    for (int off = 32; off > 0; off >>= 1) s += __shfl_down(s, off, 64);
    if (lane == 0) part[n * 128 + blockIdx.x] = s;
  }
}

// Stage 2: rinv[n] = 1 / sum_blk part[n][blk]
__global__ void softmax_fin(const float* __restrict__ part, float* __restrict__ rinv) {
  int n = blockIdx.x;          // 30
  int lane = threadIdx.x;      // 64
  float s = part[n * 128 + lane] + part[n * 128 + 64 + lane];
  #pragma unroll
  for (int off = 32; off > 0; off >>= 1) s += __shfl_down(s, off, 64);
  if (lane == 0) rinv[n] = 1.0f / s;
}

// ---------------------------------------------------------------------------
// U[b, k*300+i] = sum_m alpha[b, m-k+1] * emb[tok[b,m], i]  -> bf16, stride 928
// Salpha[b] = sum_n alpha[b,n].  alpha = expa * rinv.
// (reverted verbatim to the R5 prefetch-all-30 version)
// ---------------------------------------------------------------------------
__global__ __launch_bounds__(192) void build_U(
    const int* __restrict__ tok, const unsigned short* __restrict__ embb,
    const float* __restrict__ expa, const float* __restrict__ rinv,
    unsigned short* __restrict__ U, float* __restrict__ Salpha) {
  int b = blockIdx.x;
  int tid = threadIdx.x;
  __shared__ float alpha[NW];
  __shared__ int ltok[NW];
  if (tid < NW) {
    ltok[tid] = tok[b * NW + tid];
    alpha[tid] = expa[(size_t)b * EXPA_LD + tid] * rinv[tid];
  }
  __syncthreads();
  if (tid == 0) {
    float s = 0.f;
    #pragma unroll
    for (int n = 0; n < NW; ++n) s += alpha[n];
    Salpha[b] = s;
  }
  unsigned short* Ub = U + (size_t)b * U_LD;
  if (tid < 150) {
    // Issue all 30 gathers (independent, fully unrolled -> 30 loads in flight)
    unsigned int uv[NW];
    #pragma unroll
    for (int m = 0; m < NW; ++m)
      uv[m] = *(const unsigned int*)(embb + (size_t)ltok[m] * EMB_LD + 2 * tid);
    // Broadcast alphas to registers (uniform ds_read, no conflicts)
    float al[NW];
    #pragma unroll
    for (int m = 0; m < NW; ++m) al[m] = alpha[m];

    float a0 = 0.f, a1 = 0.f, a2 = 0.f;   // col x = 2*tid
    float b0 = 0.f, b1 = 0.f, b2 = 0.f;   // col y = 2*tid+1
    #pragma unroll
    for (int m = 0; m < NW; ++m) {
      float w0 = (m + 1 < NW) ? al[m + 1] : 0.f;
      float w1 = al[m];
      float w2 = (m >= 1) ? al[m - 1] : 0.f;
      float x = blo(uv[m]), y = bhi(uv[m]);
      a0 = fmaf(w0, x, a0); b0 = fmaf(w0, y, b0);
      a1 = fmaf(w1, x, a1); b1 = fmaf(w1, y, b1);
      a2 = fmaf(w2, x, a2); b2 = fmaf(w2, y, b2);
    }
    *(unsigned int*)(Ub + 2 * tid)       = pack2bf(a0, b0);
    *(unsigned int*)(Ub + 300 + 2 * tid) = pack2bf(a1, b1);
    *(unsigned int*)(Ub + 600 + 2 * tid) = pack2bf(a2, b2);
  } else if (tid < 164) {
    *(unsigned int*)(Ub + 900 + 2 * (tid - 150)) = 0u;   // zero pad 900..927
  }
}

// ---------------------------------------------------------------------------
extern "C" void kernel_launch(void* const* d_in, const int* in_sizes, int n_in,
                              void* d_out, int out_size, void* d_ws, size_t ws_size,
                              hipStream_t stream) {
  const int*   tok    = (const int*)d_in[0];
  const float* emb    = (const float*)d_in[1];
  const float* conv_w = (const float*)d_in[2];
  const float* conv_b = (const float*)d_in[3];
  const float* v      = (const float*)d_in[4];
  const float* vb     = (const float*)d_in[5];
  const float* q      = (const float*)d_in[6];
  float* out = (float*)d_out;

  // Workspace layout (byte offsets). Total ~87.8 MB.
  char* wb = (char*)d_ws;
  float* bias2           = (float*)(wb + 0);          // 200 f32
  float* rinv            = (float*)(wb + 4096);       // 30 f32
  float* part            = (float*)(wb + 8192);       // 30*128 f32 -> 23552
  float* q2s             = (float*)(wb + 23552);      // 200 f32
  float* qsum            = (float*)(wb + 24448);      // 1 f32
  float* Salpha          = (float*)(wb + 24576);      // 32768 f32 -> 155648
  float* expa            = (float*)(wb + 155648);     // 32768*32 f32 -> 4349952
  unsigned short* embb   = (unsigned short*)(wb + 5070848);   // 20.48MB -> 25550848
  unsigned short* MtT    = (unsigned short*)(wb + 25550848);  // 409600 -> 25960448
  unsigned short* WcT    = (unsigned short*)(wb + 25960448);  // 950272 -> 26910720
  unsigned short* big    = (unsigned short*)(wb + 26910720);  // E3 u8 (20.5MB) / U (60.8MB)
  unsigned char* E3 = (unsigned char*)big;
  unsigned short* U = big;   // E3 dead after scores_kernel

  // 1. Prep
  hipLaunchKernelGGL(prep_MtT_bias, dim3(642), dim3(320), 0, stream,
                     conv_w, conv_b, v, vb, q, MtT, bias2, q2s, qsum);
  hipLaunchKernelGGL(prep_WcT, dim3(WCT_ROWS), dim3(256), 0, stream, conv_w, WcT);
  hipLaunchKernelGGL(prep_emb_bf16, dim3((VOCAB * EMB_LD) / 256), dim3(256), 0, stream,
                     emb, embb);
  // 2. E3[32000,640]u8 = quant(embb @ MtT^T)+128, bias2 folded into cols [200,400)
  hipLaunchKernelGGL((gemm_mfma<1>), dim3(E3_LDB / 128, VOCAB / 128), dim3(256), 0, stream,
                     embb, EMB_LD, MtT, EMB_LD, (void*)E3, E3_LDB, E3_LDB, EMB_LD,
                     (const float*)nullptr, (const float*)nullptr, bias2);
  // 3. exp(scores) -> expa[b][n]  (rolling-window uint8 gather, LDS reduce)
  hipLaunchKernelGGL(scores_kernel, dim3(BT / 4), dim3(256), 0, stream,
                     tok, E3, q2s, qsum, expa);
  // 4. Softmax denominators (2-stage, deterministic)
  hipLaunchKernelGGL(softmax_part, dim3(128), dim3(256), 0, stream, expa, part);
  hipLaunchKernelGGL(softmax_fin, dim3(NW), dim3(64), 0, stream, part, rinv);
  // 5. U[32768,928]bf16 + Salpha
  hipLaunchKernelGGL(build_U, dim3(BT), dim3(192), 0, stream,
                     tok, embb, expa, rinv, U, Salpha);
  // 6. out[32768,400]f32 = U @ WcT^T + Salpha ⊗ conv_b
  hipLaunchKernelGGL((gemm_mfma<0>), dim3(WCT_ROWS / 128, BT / 128), dim3(256), 0, stream,
                     U, U_LD, WcT, U_LD, (void*)out, CH, CH, U_LD,
                     Salpha, conv_b, (const float*)nullptr);
}

// Round 8
// 392.258 us; speedup vs baseline: 1.0417x; 1.0370x over previous
//
#include <hip/hip_runtime.h>
#include <cstdint>
#include <cstddef>

// Problem constants
#define BT     32768   // batch (titles)
#define NW     30      // words per title
#define VOCAB  32000
#define WD     300     // word dim
#define CH     400     // conv channels
#define AD     200     // attention dim

// Padded layouts
#define EMB_LD   320   // emb_bf16 [VOCAB][320]  (300 + pad)
#define E3_LDB   640   // E3 uint8 [VOCAB][640] bytes (600 + pad), biased +128
#define U_LD     928   // U bf16 [BT][928]       (900 + pad)
#define WCT_ROWS 512   // WcT bf16 [512][928]    (400 + pad rows)
#define EXPA_LD  32    // expa [BT][32]          (30 + pad)

#define TWO_LOG2E 2.8853900817779268f   // 2*log2(e): E3 holds 2s*log2e -> exp2 direct
#define QRANGE 14.0f                    // int8 scale range for E3 (~4 sigma; clips saturate tanh)
#define QSC  (127.0f / QRANGE)
#define QDEC (QRANGE / 127.0f)
#define QB3  (-384.0f * QDEC)           // 3-segment byte bias (each byte +128)

typedef __attribute__((ext_vector_type(8))) short bf16x8;
typedef __attribute__((ext_vector_type(4))) float f32x4;

__device__ __forceinline__ float blo(unsigned int u) {
  union { unsigned int i; float f; } x; x.i = u << 16; return x.f;
}
__device__ __forceinline__ float bhi(unsigned int u) {
  union { unsigned int i; float f; } x; x.i = u & 0xffff0000u; return x.f;
}
__device__ __forceinline__ unsigned short f2bf(float f) {
  union { float f; unsigned int i; } x; x.f = f;
  unsigned int r = x.i + 0x7FFFu + ((x.i >> 16) & 1u);   // RNE
  return (unsigned short)(r >> 16);
}
__device__ __forceinline__ unsigned int pack2bf(float a, float b) {
  return (unsigned int)f2bf(a) | ((unsigned int)f2bf(b) << 16);
}
__device__ __forceinline__ float fexp2(float x) {
#if __has_builtin(__builtin_amdgcn_exp2f)
  return __builtin_amdgcn_exp2f(x);
#else
  float r; asm volatile("v_exp_f32 %0, %1" : "=v"(r) : "v"(x)); return r;
#endif
}
// unsigned byte j of packed u, as float (compiler emits v_cvt_f32_ubyteN)
#define UBF(u, j) ((float)(((u) >> (8 * (j))) & 0xffu))

// async global->LDS, 16B per lane (global_load_lds_dwordx4)
__device__ __forceinline__ void gload16(const void* g, void* l) {
  __builtin_amdgcn_global_load_lds(
      (const __attribute__((address_space(1))) void*)g,
      (__attribute__((address_space(3))) void*)l, 16, 0, 0);
}

// ---------------------------------------------------------------------------
// Fused prep (write-major over MtT):
// block n<640: MtT[n][i] = bf16(2*log2e * sum_c conv_w[c,i,k]*v[c,d]),
//              n = k*200+d, zero for n>=600 or i>=300.
// block 640: bias2[d] = 2*log2e * (sum_c conv_b[c]*v[c,d] + vb[d])
// block 641: q2s[d] = -2*q[d]; qsum[0] = sum_d q[d]
// ---------------------------------------------------------------------------
__global__ void prep_MtT_bias(const float* __restrict__ conv_w,
                              const float* __restrict__ conv_b,
                              const float* __restrict__ v,
                              const float* __restrict__ vb,
                              const float* __restrict__ q,
                              unsigned short* __restrict__ MtT,
                              float* __restrict__ bias2,
                              float* __restrict__ q2s,
                              float* __restrict__ qsum) {
  int blk = blockIdx.x;      // 0..639 -> MtT row; 640 -> bias2; 641 -> q2s/qsum
  int i = threadIdx.x;       // 0..319
  if (blk < 640) {
    float val = 0.f;
    if (blk < 600 && i < WD) {
      int k = blk / AD, d = blk - k * AD;
      float acc = 0.f;
      #pragma unroll 4
      for (int c = 0; c < CH; ++c)
        acc += conv_w[(c * WD + i) * 3 + k] * v[c * AD + d];
      val = TWO_LOG2E * acc;
    }
    MtT[blk * EMB_LD + i] = f2bf(val);
  } else if (blk == 640) {
    if (i < AD) {
      float acc = vb[i];
      #pragma unroll 4
      for (int c = 0; c < CH; ++c)
        acc += conv_b[c] * v[c * AD + i];
      bias2[i] = TWO_LOG2E * acc;
    }
  } else {
    if (i < AD) q2s[i] = -2.0f * q[i];
    if (i == 0) {
      float s = 0.f;
      for (int j = 0; j < AD; ++j) s += q[j];
      qsum[0] = s;
    }
  }
}

// WcT[c][kk] = bf16(conv_w[c, i, k]), kk = k*300+i; zero-padded. [512][928]
__global__ void prep_WcT(const float* __restrict__ conv_w, unsigned short* __restrict__ WcT) {
  int c = blockIdx.x;    // 512
  for (int kk = threadIdx.x; kk < U_LD; kk += 256) {
    float val = 0.f;
    if (c < CH && kk < 900) {
      int k = kk / WD, i = kk - k * WD;
      val = conv_w[(c * WD + i) * 3 + k];
    }
    WcT[(size_t)c * U_LD + kk] = f2bf(val);
  }
}

// emb -> bf16, zero-padded cols. [VOCAB][320]
__global__ void prep_emb_bf16(const float* __restrict__ emb, unsigned short* __restrict__ embb) {
  int idx = blockIdx.x * 256 + threadIdx.x;
  if (idx >= VOCAB * EMB_LD) return;
  int r = idx / EMB_LD, c = idx - r * EMB_LD;
  embb[idx] = (c < WD) ? f2bf(emb[(size_t)r * WD + c]) : (unsigned short)0;
}

// ---------------------------------------------------------------------------
// bf16 MFMA GEMM: C[M,N] = A[M,K] @ Bt[N,K]^T. 128x128 tile, K-step 32.
// R8: T3 "minimum 2-phase" double-buffer. Two 16KB linear LDS buffers;
// each iteration: issue 4 async gload16 for tile t+1 into buf^1 FIRST,
// then ds_read+MFMA tile t from buf[cur], then ONE __syncthreads() (its
// implicit vmcnt(0) drain lands the prefetch; barrier retires readers).
// Load latency hides under the current tile's compute; 1 barrier/K-step.
// (R7's single-buffer exposed full load latency serially each step.)
// MODE 1: biased-uint8 store (quantize by QSC, +128), e3bias on cols [200,400).
// MODE 0: fp32 store with col<N guard + rank-1 bias_m[r]*bias_n[c].
// XCD-chunked bijective block swizzle (m204) for A-panel L2 locality.
// ---------------------------------------------------------------------------
template<int MODE>
__global__ __launch_bounds__(256) void gemm_mfma(
    const unsigned short* __restrict__ A, int lda,
    const unsigned short* __restrict__ Bt, int ldb,
    void* __restrict__ Cp, int ldc, int N, int K,
    const float* __restrict__ bias_m, const float* __restrict__ bias_n,
    const float* __restrict__ e3bias) {
  __shared__ __align__(16) char lds[2][16384];   // per buf: A 8KB | B 8KB
  int tid = threadIdx.x;
  int lane = tid & 63, wave = tid >> 6;

  // XCD-aware bijective swizzle: contiguous tile chunks per XCD.
  int gx = gridDim.x;
  int nwg = gx * (int)gridDim.y;
  int orig = blockIdx.y * gx + blockIdx.x;
  int xcd = orig & 7, qq = nwg >> 3, rr = nwg & 7;
  int wg = (xcd < rr ? xcd * (qq + 1) : rr * (qq + 1) + (xcd - rr) * qq) + (orig >> 3);
  int row0 = (wg / gx) * 128, col0 = (wg % gx) * 128;

  int wm = (wave & 1) * 64, wn = (wave >> 1) * 64;
  int lr = lane & 15, quad = lane >> 4;

  f32x4 acc[4][4];
  #pragma unroll
  for (int i = 0; i < 4; ++i)
    #pragma unroll
    for (int j = 0; j < 4; ++j) acc[i][j] = (f32x4){0.f, 0.f, 0.f, 0.f};

  int r0 = tid >> 2, ko0 = (tid & 3) * 8;   // issue0: rows 0..63
  int r1 = r0 + 64;                          // issue1: rows 64..127, same ko

  const unsigned short* gA0 = A + (size_t)(row0 + r0) * lda + ko0;
  const unsigned short* gA1 = A + (size_t)(row0 + r1) * lda + ko0;
  const unsigned short* gB0 = Bt + (size_t)(col0 + r0) * ldb + ko0;
  const unsigned short* gB1 = Bt + (size_t)(col0 + r1) * ldb + ko0;

  int nt = K >> 5;
  int cur = 0;
  // prologue: stage tile 0 into buf 0
  {
    char* nb = lds[0];
    gload16(gA0, nb + tid * 16);
    gload16(gA1, nb + 4096 + tid * 16);
    gload16(gB0, nb + 8192 + tid * 16);
    gload16(gB1, nb + 12288 + tid * 16);
  }
  __syncthreads();                       // vmcnt(0) drain: tile 0 resident

  for (int t = 0; t < nt; ++t) {
    if (t + 1 < nt) {                    // prefetch tile t+1 into other buf
      char* nb = lds[cur ^ 1];
      int kk = (t + 1) << 5;
      gload16(gA0 + kk, nb + tid * 16);
      gload16(gA1 + kk, nb + 4096 + tid * 16);
      gload16(gB0 + kk, nb + 8192 + tid * 16);
      gload16(gB1 + kk, nb + 12288 + tid * 16);
    }
    char* base = lds[cur];
    bf16x8 af[4], bfr[4];
    #pragma unroll
    for (int mi = 0; mi < 4; ++mi)
      af[mi] = *(const bf16x8*)(base + (wm + mi * 16 + lr) * 64 + quad * 16);
    #pragma unroll
    for (int ni = 0; ni < 4; ++ni)
      bfr[ni] = *(const bf16x8*)(base + 8192 + (wn + ni * 16 + lr) * 64 + quad * 16);
    #pragma unroll
    for (int mi = 0; mi < 4; ++mi)
      #pragma unroll
      for (int ni = 0; ni < 4; ++ni)
        acc[mi][ni] = __builtin_amdgcn_mfma_f32_16x16x32_bf16(
            af[mi], bfr[ni], acc[mi][ni], 0, 0, 0);
    __syncthreads();   // implicit vmcnt(0): prefetch landed; buf[cur] free
    cur ^= 1;
  }

  // Epilogue. C/D layout: col = lane&15, row = quad*4 + reg.
  if (MODE == 1) {
    unsigned char* C = (unsigned char*)Cp;
    #pragma unroll
    for (int mi = 0; mi < 4; ++mi)
      #pragma unroll
      for (int ni = 0; ni < 4; ++ni) {
        int c = col0 + wn + ni * 16 + lr;
        float cb = (e3bias && c >= 200 && c < 400) ? e3bias[c - 200] : 0.f;
        #pragma unroll
        for (int reg = 0; reg < 4; ++reg) {
          int r = row0 + wm + mi * 16 + quad * 4 + reg;
          float x = (acc[mi][ni][reg] + cb) * QSC;
          int qi = (int)rintf(x);
          qi = qi > 127 ? 127 : (qi < -127 ? -127 : qi);
          C[(size_t)r * ldc + c] = (unsigned char)(qi + 128);
        }
      }
  } else {
    float* C = (float*)Cp;
    #pragma unroll
    for (int mi = 0; mi < 4; ++mi)
      #pragma unroll
      for (int ni = 0; ni < 4; ++ni) {
        int c = col0 + wn + ni * 16 + lr;
        if (c < N) {
          float bn = bias_n[c];
          #pragma unroll
          for (int reg = 0; reg < 4; ++reg) {
            int r = row0 + wm + mi * 16 + quad * 4 + reg;
            C[(size_t)r * ldc + c] = acc[mi][ni][reg] + bias_m[r] * bn;
          }
        }
      }
  }
}

// ---------------------------------------------------------------------------
// Scores, TITLE-per-wave, ROLLING-WINDOW over tokens, biased-uint8 E3.
// (R5 version verbatim: 89us, VALUBusy ~100%)
// ---------------------------------------------------------------------------
__global__ __launch_bounds__(256) void scores_kernel(
    const int* __restrict__ tok, const unsigned char* __restrict__ E3,
    const float* __restrict__ q2s, const float* __restrict__ qsum,
    float* __restrict__ expa) {
  __shared__ float qs[AD];
  __shared__ __align__(16) float red[4][NW][36];   // stride 36 floats = 144B (16B aligned)
  int tid = threadIdx.x;
  if (tid < AD) qs[tid] = q2s[tid];
  __syncthreads();
  int wave = tid >> 6, lane = tid & 63;
  int b = blockIdx.x * 4 + wave;
  int tk = tok[b * NW + ((lane < NW) ? lane : 0)];
  int d0 = (lane < 50) ? lane * 4 : 0;
  float4 qv = make_float4(0.f, 0.f, 0.f, 0.f);
  if (lane < 50) qv = *(const float4*)&qs[d0];   // lanes >=50 contribute 0
  float s01 = qv.x + qv.y, s23 = qv.z + qv.w;
  float Qsum = qsum[0];
  float* myred = &red[wave][0][lane >> 1];       // word stride = 36 floats

  // Prefetch row tok[0]: three 4B segment loads off one base.
  int t0r = __shfl(tk, 0, 64);
  const unsigned char* r0p = E3 + (size_t)(unsigned)t0r * E3_LDB + d0;
  unsigned int a0 = *(const unsigned int*)(r0p);          // seg0 -> s[1]
  unsigned int a1 = *(const unsigned int*)(r0p + 200);    // seg1 -> s[0]
  unsigned int a2 = *(const unsigned int*)(r0p + 400);    // seg2 -> s[-1] (dropped)

  // fp32 window of biased bytes; virtual seg0(tok[-1]) = bias 128.
  float P0 = 0.f, P1 = 0.f, P2 = 0.f, P3 = 0.f;
  float Q0 = 128.f, Q1 = 128.f, Q2 = 128.f, Q3 = 128.f;

  #pragma unroll
  for (int m = 0; m < NW; ++m) {
    unsigned int u0 = a0, u1 = a1, u2 = a2;
    if (m + 1 < NW) {   // prefetch next token's row (independent of below)
      int tn = __shfl(tk, m + 1, 64);
      const unsigned char* rp = E3 + (size_t)(unsigned)tn * E3_LDB + d0;
      a0 = *(const unsigned int*)(rp);
      a1 = *(const unsigned int*)(rp + 200);
      a2 = *(const unsigned int*)(rp + 400);
    }
    if (m > 0) {
      // complete s[m-1] with seg2 of current row; sigmoid; pair-park.
      float e0 = fexp2(fmaf(P0 + UBF(u2, 0), QDEC, QB3));
      float e1 = fexp2(fmaf(P1 + UBF(u2, 1), QDEC, QB3));
      float e2 = fexp2(fmaf(P2 + UBF(u2, 2), QDEC, QB3));
      float e3 = fexp2(fmaf(P3 + UBF(u2, 3), QDEC, QB3));
      float n01 = fmaf(qv.x, e1, s01); n01 = fmaf(qv.y, e0, n01);
      float n23 = fmaf(qv.z, e3, s23); n23 = fmaf(qv.w, e2, n23);
      float d01 = fmaf(e0, e1, (e0 + e1) + 1.0f);
      float d23 = fmaf(e2, e3, (e2 + e3) + 1.0f);
      float acc = n01 * __builtin_amdgcn_rcpf(d01);
      acc = fmaf(n23, __builtin_amdgcn_rcpf(d23), acc);
      acc += __shfl_xor(acc, 1, 64);          // lanes 2k,2k+1 now equal
      myred[(m - 1) * 36] = acc;              // benign same-value dual write
    }
    // advance window: P' = Q + seg1(tok[m]); Q' = seg0(tok[m])
    P0 = Q0 + UBF(u1, 0); P1 = Q1 + UBF(u1, 1);
    P2 = Q2 + UBF(u1, 2); P3 = Q3 + UBF(u1, 3);
    Q0 = UBF(u0, 0); Q1 = UBF(u0, 1);
    Q2 = UBF(u0, 2); Q3 = UBF(u0, 3);
  }
  { // epilogue: s[29] complete; missing seg2 -> bias 128
    float e0 = fexp2(fmaf(P0 + 128.f, QDEC, QB3));
    float e1 = fexp2(fmaf(P1 + 128.f, QDEC, QB3));
    float e2 = fexp2(fmaf(P2 + 128.f, QDEC, QB3));
    float e3 = fexp2(fmaf(P3 + 128.f, QDEC, QB3));
    float n01 = fmaf(qv.x, e1, s01); n01 = fmaf(qv.y, e0, n01);
    float n23 = fmaf(qv.z, e3, s23); n23 = fmaf(qv.w, e2, n23);
    float d01 = fmaf(e0, e1, (e0 + e1) + 1.0f);
    float d23 = fmaf(e2, e3, (e2 + e3) + 1.0f);
    float acc = n01 * __builtin_amdgcn_rcpf(d01);
    acc = fmaf(n23, __builtin_amdgcn_rcpf(d23), acc);
    acc += __shfl_xor(acc, 1, 64);
    myred[(NW - 1) * 36] = acc;
  }
  __syncthreads();
  // Transpose-reduce: word n's 32 partials; lane n sums j=0..15, lane n+32
  // sums j=16..31; xor-32 combines. Lanes with n>=30 are dummies.
  int n = lane & 31; if (n >= NW) n = 0;
  int half = lane >> 5;
  const float4* rp4 = (const float4*)&red[wave][n][half * 16];
  float4 s4 = rp4[0];
  #pragma unroll
  for (int j = 1; j < 4; ++j) {
    float4 vv = rp4[j];
    s4.x += vv.x; s4.y += vv.y; s4.z += vv.z; s4.w += vv.w;
  }
  float tot = (s4.x + s4.y) + (s4.z + s4.w);
  tot += __shfl_xor(tot, 32, 64);
  // |score| <= sum|q| ~ 16 -> exp safe in fp32; softmax needs no max-shift.
  float e = __expf(Qsum + tot);
  if (lane < NW) expa[(size_t)b * EXPA_LD + lane] = e;
}

// ---------------------------------------------------------------------------
// Softmax-over-batch denominators, stage 1: 128 blocks x 256 titles each.
// part[n][blk] = sum over block's titles of expa[b][n].
// ---------------------------------------------------------------------------
__global__ __launch_bounds__(256) void softmax_part(const float* __restrict__ expa,
                                                    float* __restrict__ part) {
  __shared__ float P[256][33];
  int tid = threadIdx.x;
  const float* row = expa + (size_t)(blockIdx.x * 256 + tid) * EXPA_LD;
  #pragma unroll
  for (int j = 0; j < 7; ++j) {
    float4 vv = *(const float4*)(row + j * 4);
    P[tid][j * 4] = vv.x; P[tid][j * 4 + 1] = vv.y;
    P[tid][j * 4 + 2] = vv.z; P[tid][j * 4 + 3] = vv.w;
  }
  P[tid][28] = row[28]; P[tid][29] = row[29];
  __syncthreads();
  int wave = tid >> 6, lane = tid & 63;
  for (int n = wave * 8; n < wave * 8 + 8 && n < NW; ++n) {
    float s = P[lane * 4][n] + P[lane * 4 + 1][n] + P[lane * 4 + 2][n] + P[lane * 4 + 3][n];
    #pragma unroll
    for (int off = 32; off > 0; off >>= 1) s += __shfl_down(s, off, 64);
    if (lane == 0) part[n * 128 + blockIdx.x] = s;
  }
}

// Stage 2: rinv[n] = 1 / sum_blk part[n][blk]
__global__ void softmax_fin(const float* __restrict__ part, float* __restrict__ rinv) {
  int n = blockIdx.x;          // 30
  int lane = threadIdx.x;      // 64
  float s = part[n * 128 + lane] + part[n * 128 + 64 + lane];
  #pragma unroll
  for (int off = 32; off > 0; off >>= 1) s += __shfl_down(s, off, 64);
  if (lane == 0) rinv[n] = 1.0f / s;
}

// ---------------------------------------------------------------------------
// U[b, k*300+i] = sum_m alpha[b, m-k+1] * emb[tok[b,m], i]  -> bf16, stride 928
// Salpha[b] = sum_n alpha[b,n].  alpha = expa * rinv.
// (R5 prefetch-all-30 version verbatim)
// ---------------------------------------------------------------------------
__global__ __launch_bounds__(192) void build_U(
    const int* __restrict__ tok, const unsigned short* __restrict__ embb,
    const float* __restrict__ expa, const float* __restrict__ rinv,
    unsigned short* __restrict__ U, float* __restrict__ Salpha) {
  int b = blockIdx.x;
  int tid = threadIdx.x;
  __shared__ float alpha[NW];
  __shared__ int ltok[NW];
  if (tid < NW) {
    ltok[tid] = tok[b * NW + tid];
    alpha[tid] = expa[(size_t)b * EXPA_LD + tid] * rinv[tid];
  }
  __syncthreads();
  if (tid == 0) {
    float s = 0.f;
    #pragma unroll
    for (int n = 0; n < NW; ++n) s += alpha[n];
    Salpha[b] = s;
  }
  unsigned short* Ub = U + (size_t)b * U_LD;
  if (tid < 150) {
    // Issue all 30 gathers (independent, fully unrolled -> 30 loads in flight)
    unsigned int uv[NW];
    #pragma unroll
    for (int m = 0; m < NW; ++m)
      uv[m] = *(const unsigned int*)(embb + (size_t)ltok[m] * EMB_LD + 2 * tid);
    // Broadcast alphas to registers (uniform ds_read, no conflicts)
    float al[NW];
    #pragma unroll
    for (int m = 0; m < NW; ++m) al[m] = alpha[m];

    float a0 = 0.f, a1 = 0.f, a2 = 0.f;   // col x = 2*tid
    float b0 = 0.f, b1 = 0.f, b2 = 0.f;   // col y = 2*tid+1
    #pragma unroll
    for (int m = 0; m < NW; ++m) {
      float w0 = (m + 1 < NW) ? al[m + 1] : 0.f;
      float w1 = al[m];
      float w2 = (m >= 1) ? al[m - 1] : 0.f;
      float x = blo(uv[m]), y = bhi(uv[m]);
      a0 = fmaf(w0, x, a0); b0 = fmaf(w0, y, b0);
      a1 = fmaf(w1, x, a1); b1 = fmaf(w1, y, b1);
      a2 = fmaf(w2, x, a2); b2 = fmaf(w2, y, b2);
    }
    *(unsigned int*)(Ub + 2 * tid)       = pack2bf(a0, b0);
    *(unsigned int*)(Ub + 300 + 2 * tid) = pack2bf(a1, b1);
    *(unsigned int*)(Ub + 600 + 2 * tid) = pack2bf(a2, b2);
  } else if (tid < 164) {
    *(unsigned int*)(Ub + 900 + 2 * (tid - 150)) = 0u;   // zero pad 900..927
  }
}

// ---------------------------------------------------------------------------
extern "C" void kernel_launch(void* const* d_in, const int* in_sizes, int n_in,
                              void* d_out, int out_size, void* d_ws, size_t ws_size,
                              hipStream_t stream) {
  const int*   tok    = (const int*)d_in[0];
  const float* emb    = (const float*)d_in[1];
  const float* conv_w = (const float*)d_in[2];
  const float* conv_b = (const float*)d_in[3];
  const float* v      = (const float*)d_in[4];
  const float* vb     = (const float*)d_in[5];
  const float* q      = (const float*)d_in[6];
  float* out = (float*)d_out;

  // Workspace layout (byte offsets). Total ~87.8 MB.
  char* wb = (char*)d_ws;
  float* bias2           = (float*)(wb + 0);          // 200 f32
  float* rinv            = (float*)(wb + 4096);       // 30 f32
  float* part            = (float*)(wb + 8192);       // 30*128 f32 -> 23552
  float* q2s             = (float*)(wb + 23552);      // 200 f32
  float* qsum            = (float*)(wb + 24448);      // 1 f32
  float* Salpha          = (float*)(wb + 24576);      // 32768 f32 -> 155648
  float* expa            = (float*)(wb + 155648);     // 32768*32 f32 -> 4349952
  unsigned short* embb   = (unsigned short*)(wb + 5070848);   // 20.48MB -> 25550848
  unsigned short* MtT    = (unsigned short*)(wb + 25550848);  // 409600 -> 25960448
  unsigned short* WcT    = (unsigned short*)(wb + 25960448);  // 950272 -> 26910720
  unsigned short* big    = (unsigned short*)(wb + 26910720);  // E3 u8 (20.5MB) / U (60.8MB)
  unsigned char* E3 = (unsigned char*)big;
  unsigned short* U = big;   // E3 dead after scores_kernel

  // 1. Prep
  hipLaunchKernelGGL(prep_MtT_bias, dim3(642), dim3(320), 0, stream,
                     conv_w, conv_b, v, vb, q, MtT, bias2, q2s, qsum);
  hipLaunchKernelGGL(prep_WcT, dim3(WCT_ROWS), dim3(256), 0, stream, conv_w, WcT);
  hipLaunchKernelGGL(prep_emb_bf16, dim3((VOCAB * EMB_LD) / 256), dim3(256), 0, stream,
                     emb, embb);
  // 2. E3[32000,640]u8 = quant(embb @ MtT^T)+128, bias2 folded into cols [200,400)
  hipLaunchKernelGGL((gemm_mfma<1>), dim3(E3_LDB / 128, VOCAB / 128), dim3(256), 0, stream,
                     embb, EMB_LD, MtT, EMB_LD, (void*)E3, E3_LDB, E3_LDB, EMB_LD,
                     (const float*)nullptr, (const float*)nullptr, bias2);
  // 3. exp(scores) -> expa[b][n]  (rolling-window uint8 gather, LDS reduce)
  hipLaunchKernelGGL(scores_kernel, dim3(BT / 4), dim3(256), 0, stream,
                     tok, E3, q2s, qsum, expa);
  // 4. Softmax denominators (2-stage, deterministic)
  hipLaunchKernelGGL(softmax_part, dim3(128), dim3(256), 0, stream, expa, part);
  hipLaunchKernelGGL(softmax_fin, dim3(NW), dim3(64), 0, stream, part, rinv);
  // 5. U[32768,928]bf16 + Salpha
  hipLaunchKernelGGL(build_U, dim3(BT), dim3(192), 0, stream,
                     tok, embb, expa, rinv, U, Salpha);
  // 6. out[32768,400]f32 = U @ WcT^T + Salpha ⊗ conv_b
  hipLaunchKernelGGL((gemm_mfma<0>), dim3(WCT_ROWS / 128, BT / 128), dim3(256), 0, stream,
                     U, U_LD, WcT, U_LD, (void*)out, CH, CH, U_LD,
                     Salpha, conv_b, (const float*)nullptr);
}

// Round 9
// 390.540 us; speedup vs baseline: 1.0462x; 1.0044x over previous
//
#include <hip/hip_runtime.h>
#include <cstdint>
#include <cstddef>

// Problem constants
#define BT     32768   // batch (titles)
#define NW     30      // words per title
#define VOCAB  32000
#define WD     300     // word dim
#define CH     400     // conv channels
#define AD     200     // attention dim

// Padded layouts
#define EMB_LD   320   // emb_bf16 [VOCAB][320]  (300 + pad)
#define E3_LDB   640   // E3 uint8 [VOCAB][640] bytes (600 + pad), biased +128
#define U_LD     928   // U bf16 [BT][928]       (900 + pad)
#define WCT_ROWS 512   // WcT bf16 [512][928]    (400 + pad rows)
#define EXPA_LD  32    // expa [BT][32]          (30 + pad)

#define TWO_LOG2E 2.8853900817779268f   // 2*log2(e): E3 holds 2s*log2e -> exp2 direct
#define QRANGE 14.0f                    // int8 scale range for E3 (~4 sigma; clips saturate tanh)
#define QSC  (127.0f / QRANGE)
#define QDEC (QRANGE / 127.0f)
#define QB3  (-384.0f * QDEC)           // 3-segment byte bias (each byte +128)

typedef __attribute__((ext_vector_type(8))) short bf16x8;
typedef __attribute__((ext_vector_type(4))) float f32x4;

__device__ __forceinline__ float blo(unsigned int u) {
  union { unsigned int i; float f; } x; x.i = u << 16; return x.f;
}
__device__ __forceinline__ float bhi(unsigned int u) {
  union { unsigned int i; float f; } x; x.i = u & 0xffff0000u; return x.f;
}
__device__ __forceinline__ unsigned short f2bf(float f) {
  union { float f; unsigned int i; } x; x.f = f;
  unsigned int r = x.i + 0x7FFFu + ((x.i >> 16) & 1u);   // RNE
  return (unsigned short)(r >> 16);
}
__device__ __forceinline__ unsigned int pack2bf(float a, float b) {
  return (unsigned int)f2bf(a) | ((unsigned int)f2bf(b) << 16);
}
__device__ __forceinline__ float fexp2(float x) {
#if __has_builtin(__builtin_amdgcn_exp2f)
  return __builtin_amdgcn_exp2f(x);
#else
  float r; asm volatile("v_exp_f32 %0, %1" : "=v"(r) : "v"(x)); return r;
#endif
}
// unsigned byte j of packed u, as float (compiler emits v_cvt_f32_ubyteN)
#define UBF(u, j) ((float)(((u) >> (8 * (j))) & 0xffu))

// async global->LDS, 16B per lane (global_load_lds_dwordx4)
__device__ __forceinline__ void gload16(const void* g, void* l) {
  __builtin_amdgcn_global_load_lds(
      (const __attribute__((address_space(1))) void*)g,
      (__attribute__((address_space(3))) void*)l, 16, 0, 0);
}

// ---------------------------------------------------------------------------
// Fused prep (write-major over MtT). R9: LDS-stage the broadcast column so
// the 400-deep reduction issues INDEPENDENT coalesced-ish conv_w loads
// (unroll 8) instead of 400 serial stride-800B scalar loads per thread.
// block n<640: MtT[n][i] = bf16(2*log2e * sum_c conv_w[c,i,k]*v[c,d]),
//              n = k*200+d, zero for n>=600 or i>=300.
// block 640: bias2[d] = 2*log2e * (sum_c conv_b[c]*v[c,d] + vb[d])
// block 641: q2s[d] = -2*q[d]; qsum[0] = sum_d q[d]
// ---------------------------------------------------------------------------
__global__ __launch_bounds__(320) void prep_MtT_bias(
    const float* __restrict__ conv_w,
    const float* __restrict__ conv_b,
    const float* __restrict__ v,
    const float* __restrict__ vb,
    const float* __restrict__ q,
    unsigned short* __restrict__ MtT,
    float* __restrict__ bias2,
    float* __restrict__ q2s,
    float* __restrict__ qsum) {
  __shared__ float col[CH];
  int blk = blockIdx.x;      // 0..639 -> MtT row; 640 -> bias2; 641 -> q2s/qsum
  int i = threadIdx.x;       // 0..319
  if (blk < 640) {
    int k = blk / AD, d = blk - k * AD;   // valid for blk<600
    if (blk < 600) {
      for (int c = i; c < CH; c += 320) col[c] = v[c * AD + d];
    }
    __syncthreads();
    float val = 0.f;
    if (blk < 600 && i < WD) {
      const float* wp = conv_w + i * 3 + k;   // conv_w[c*900 + i*3 + k]
      float acc = 0.f;
      #pragma unroll 8
      for (int c = 0; c < CH; ++c)
        acc = fmaf(wp[(size_t)c * 900], col[c], acc);
      val = TWO_LOG2E * acc;
    }
    MtT[blk * EMB_LD + i] = f2bf(val);
  } else if (blk == 640) {
    for (int c = i; c < CH; c += 320) col[c] = conv_b[c];
    __syncthreads();
    if (i < AD) {
      float acc = vb[i];
      #pragma unroll 8
      for (int c = 0; c < CH; ++c)
        acc = fmaf(col[c], v[c * AD + i], acc);
      bias2[i] = TWO_LOG2E * acc;
    }
  } else {
    if (i < AD) q2s[i] = -2.0f * q[i];
    if (i == 0) {
      float s = 0.f;
      for (int j = 0; j < AD; ++j) s += q[j];
      qsum[0] = s;
    }
  }
}

// WcT[c][kk] = bf16(conv_w[c, i, k]), kk = k*300+i; zero-padded. [512][928]
__global__ void prep_WcT(const float* __restrict__ conv_w, unsigned short* __restrict__ WcT) {
  int c = blockIdx.x;    // 512
  for (int kk = threadIdx.x; kk < U_LD; kk += 256) {
    float val = 0.f;
    if (c < CH && kk < 900) {
      int k = kk / WD, i = kk - k * WD;
      val = conv_w[(c * WD + i) * 3 + k];
    }
    WcT[(size_t)c * U_LD + kk] = f2bf(val);
  }
}

// emb -> bf16, zero-padded cols. [VOCAB][320]
__global__ void prep_emb_bf16(const float* __restrict__ emb, unsigned short* __restrict__ embb) {
  int idx = blockIdx.x * 256 + threadIdx.x;
  if (idx >= VOCAB * EMB_LD) return;
  int r = idx / EMB_LD, c = idx - r * EMB_LD;
  embb[idx] = (c < WD) ? f2bf(emb[(size_t)r * WD + c]) : (unsigned short)0;
}

// ---------------------------------------------------------------------------
// bf16 MFMA GEMM: C[M,N] = A[M,K] @ Bt[N,K]^T. 128x128 tile, K-step 32.
// T3 "minimum 2-phase" double-buffer (R8, passing): two 16KB linear LDS
// buffers; per iter: issue 4 async gload16 for tile t+1 into buf^1, then
// ds_read+MFMA tile t, then ONE __syncthreads() (implicit vmcnt(0) lands
// the prefetch; barrier retires readers). 1 barrier/K-step.
// MODE 1: biased-uint8 store (quantize by QSC, +128), e3bias on cols [200,400).
// MODE 0: fp32 store with col<N guard + rank-1 bias_m[r]*bias_n[c].
// XCD-chunked bijective block swizzle (m204) for A-panel L2 locality.
// ---------------------------------------------------------------------------
template<int MODE>
__global__ __launch_bounds__(256) void gemm_mfma(
    const unsigned short* __restrict__ A, int lda,
    const unsigned short* __restrict__ Bt, int ldb,
    void* __restrict__ Cp, int ldc, int N, int K,
    const float* __restrict__ bias_m, const float* __restrict__ bias_n,
    const float* __restrict__ e3bias) {
  __shared__ __align__(16) char lds[2][16384];   // per buf: A 8KB | B 8KB
  int tid = threadIdx.x;
  int lane = tid & 63, wave = tid >> 6;

  // XCD-aware bijective swizzle: contiguous tile chunks per XCD.
  int gx = gridDim.x;
  int nwg = gx * (int)gridDim.y;
  int orig = blockIdx.y * gx + blockIdx.x;
  int xcd = orig & 7, qq = nwg >> 3, rr = nwg & 7;
  int wg = (xcd < rr ? xcd * (qq + 1) : rr * (qq + 1) + (xcd - rr) * qq) + (orig >> 3);
  int row0 = (wg / gx) * 128, col0 = (wg % gx) * 128;

  int wm = (wave & 1) * 64, wn = (wave >> 1) * 64;
  int lr = lane & 15, quad = lane >> 4;

  f32x4 acc[4][4];
  #pragma unroll
  for (int i = 0; i < 4; ++i)
    #pragma unroll
    for (int j = 0; j < 4; ++j) acc[i][j] = (f32x4){0.f, 0.f, 0.f, 0.f};

  int r0 = tid >> 2, ko0 = (tid & 3) * 8;   // issue0: rows 0..63
  int r1 = r0 + 64;                          // issue1: rows 64..127, same ko

  const unsigned short* gA0 = A + (size_t)(row0 + r0) * lda + ko0;
  const unsigned short* gA1 = A + (size_t)(row0 + r1) * lda + ko0;
  const unsigned short* gB0 = Bt + (size_t)(col0 + r0) * ldb + ko0;
  const unsigned short* gB1 = Bt + (size_t)(col0 + r1) * ldb + ko0;

  int nt = K >> 5;
  int cur = 0;
  // prologue: stage tile 0 into buf 0
  {
    char* nb = lds[0];
    gload16(gA0, nb + tid * 16);
    gload16(gA1, nb + 4096 + tid * 16);
    gload16(gB0, nb + 8192 + tid * 16);
    gload16(gB1, nb + 12288 + tid * 16);
  }
  __syncthreads();                       // vmcnt(0) drain: tile 0 resident

  for (int t = 0; t < nt; ++t) {
    if (t + 1 < nt) {                    // prefetch tile t+1 into other buf
      char* nb = lds[cur ^ 1];
      int kk = (t + 1) << 5;
      gload16(gA0 + kk, nb + tid * 16);
      gload16(gA1 + kk, nb + 4096 + tid * 16);
      gload16(gB0 + kk, nb + 8192 + tid * 16);
      gload16(gB1 + kk, nb + 12288 + tid * 16);
    }
    char* base = lds[cur];
    bf16x8 af[4], bfr[4];
    #pragma unroll
    for (int mi = 0; mi < 4; ++mi)
      af[mi] = *(const bf16x8*)(base + (wm + mi * 16 + lr) * 64 + quad * 16);
    #pragma unroll
    for (int ni = 0; ni < 4; ++ni)
      bfr[ni] = *(const bf16x8*)(base + 8192 + (wn + ni * 16 + lr) * 64 + quad * 16);
    #pragma unroll
    for (int mi = 0; mi < 4; ++mi)
      #pragma unroll
      for (int ni = 0; ni < 4; ++ni)
        acc[mi][ni] = __builtin_amdgcn_mfma_f32_16x16x32_bf16(
            af[mi], bfr[ni], acc[mi][ni], 0, 0, 0);
    __syncthreads();   // implicit vmcnt(0): prefetch landed; buf[cur] free
    cur ^= 1;
  }

  // Epilogue. C/D layout: col = lane&15, row = quad*4 + reg.
  if (MODE == 1) {
    unsigned char* C = (unsigned char*)Cp;
    #pragma unroll
    for (int mi = 0; mi < 4; ++mi)
      #pragma unroll
      for (int ni = 0; ni < 4; ++ni) {
        int c = col0 + wn + ni * 16 + lr;
        float cb = (e3bias && c >= 200 && c < 400) ? e3bias[c - 200] : 0.f;
        #pragma unroll
        for (int reg = 0; reg < 4; ++reg) {
          int r = row0 + wm + mi * 16 + quad * 4 + reg;
          float x = (acc[mi][ni][reg] + cb) * QSC;
          int qi = (int)rintf(x);
          qi = qi > 127 ? 127 : (qi < -127 ? -127 : qi);
          C[(size_t)r * ldc + c] = (unsigned char)(qi + 128);
        }
      }
  } else {
    float* C = (float*)Cp;
    #pragma unroll
    for (int mi = 0; mi < 4; ++mi)
      #pragma unroll
      for (int ni = 0; ni < 4; ++ni) {
        int c = col0 + wn + ni * 16 + lr;
        if (c < N) {
          float bn = bias_n[c];
          #pragma unroll
          for (int reg = 0; reg < 4; ++reg) {
            int r = row0 + wm + mi * 16 + quad * 4 + reg;
            C[(size_t)r * ldc + c] = acc[mi][ni][reg] + bias_m[r] * bn;
          }
        }
      }
  }
}

// ---------------------------------------------------------------------------
// Scores, TITLE-per-wave, ROLLING-WINDOW over tokens, biased-uint8 E3.
// (R5 version verbatim: ~90us, VALUBusy ~100%)
// ---------------------------------------------------------------------------
__global__ __launch_bounds__(256) void scores_kernel(
    const int* __restrict__ tok, const unsigned char* __restrict__ E3,
    const float* __restrict__ q2s, const float* __restrict__ qsum,
    float* __restrict__ expa) {
  __shared__ float qs[AD];
  __shared__ __align__(16) float red[4][NW][36];   // stride 36 floats = 144B (16B aligned)
  int tid = threadIdx.x;
  if (tid < AD) qs[tid] = q2s[tid];
  __syncthreads();
  int wave = tid >> 6, lane = tid & 63;
  int b = blockIdx.x * 4 + wave;
  int tk = tok[b * NW + ((lane < NW) ? lane : 0)];
  int d0 = (lane < 50) ? lane * 4 : 0;
  float4 qv = make_float4(0.f, 0.f, 0.f, 0.f);
  if (lane < 50) qv = *(const float4*)&qs[d0];   // lanes >=50 contribute 0
  float s01 = qv.x + qv.y, s23 = qv.z + qv.w;
  float Qsum = qsum[0];
  float* myred = &red[wave][0][lane >> 1];       // word stride = 36 floats

  // Prefetch row tok[0]: three 4B segment loads off one base.
  int t0r = __shfl(tk, 0, 64);
  const unsigned char* r0p = E3 + (size_t)(unsigned)t0r * E3_LDB + d0;
  unsigned int a0 = *(const unsigned int*)(r0p);          // seg0 -> s[1]
  unsigned int a1 = *(const unsigned int*)(r0p + 200);    // seg1 -> s[0]
  unsigned int a2 = *(const unsigned int*)(r0p + 400);    // seg2 -> s[-1] (dropped)

  // fp32 window of biased bytes; virtual seg0(tok[-1]) = bias 128.
  float P0 = 0.f, P1 = 0.f, P2 = 0.f, P3 = 0.f;
  float Q0 = 128.f, Q1 = 128.f, Q2 = 128.f, Q3 = 128.f;

  #pragma unroll
  for (int m = 0; m < NW; ++m) {
    unsigned int u0 = a0, u1 = a1, u2 = a2;
    if (m + 1 < NW) {   // prefetch next token's row (independent of below)
      int tn = __shfl(tk, m + 1, 64);
      const unsigned char* rp = E3 + (size_t)(unsigned)tn * E3_LDB + d0;
      a0 = *(const unsigned int*)(rp);
      a1 = *(const unsigned int*)(rp + 200);
      a2 = *(const unsigned int*)(rp + 400);
    }
    if (m > 0) {
      // complete s[m-1] with seg2 of current row; sigmoid; pair-park.
      float e0 = fexp2(fmaf(P0 + UBF(u2, 0), QDEC, QB3));
      float e1 = fexp2(fmaf(P1 + UBF(u2, 1), QDEC, QB3));
      float e2 = fexp2(fmaf(P2 + UBF(u2, 2), QDEC, QB3));
      float e3 = fexp2(fmaf(P3 + UBF(u2, 3), QDEC, QB3));
      float n01 = fmaf(qv.x, e1, s01); n01 = fmaf(qv.y, e0, n01);
      float n23 = fmaf(qv.z, e3, s23); n23 = fmaf(qv.w, e2, n23);
      float d01 = fmaf(e0, e1, (e0 + e1) + 1.0f);
      float d23 = fmaf(e2, e3, (e2 + e3) + 1.0f);
      float acc = n01 * __builtin_amdgcn_rcpf(d01);
      acc = fmaf(n23, __builtin_amdgcn_rcpf(d23), acc);
      acc += __shfl_xor(acc, 1, 64);          // lanes 2k,2k+1 now equal
      myred[(m - 1) * 36] = acc;              // benign same-value dual write
    }
    // advance window: P' = Q + seg1(tok[m]); Q' = seg0(tok[m])
    P0 = Q0 + UBF(u1, 0); P1 = Q1 + UBF(u1, 1);
    P2 = Q2 + UBF(u1, 2); P3 = Q3 + UBF(u1, 3);
    Q0 = UBF(u0, 0); Q1 = UBF(u0, 1);
    Q2 = UBF(u0, 2); Q3 = UBF(u0, 3);
  }
  { // epilogue: s[29] complete; missing seg2 -> bias 128
    float e0 = fexp2(fmaf(P0 + 128.f, QDEC, QB3));
    float e1 = fexp2(fmaf(P1 + 128.f, QDEC, QB3));
    float e2 = fexp2(fmaf(P2 + 128.f, QDEC, QB3));
    float e3 = fexp2(fmaf(P3 + 128.f, QDEC, QB3));
    float n01 = fmaf(qv.x, e1, s01); n01 = fmaf(qv.y, e0, n01);
    float n23 = fmaf(qv.z, e3, s23); n23 = fmaf(qv.w, e2, n23);
    float d01 = fmaf(e0, e1, (e0 + e1) + 1.0f);
    float d23 = fmaf(e2, e3, (e2 + e3) + 1.0f);
    float acc = n01 * __builtin_amdgcn_rcpf(d01);
    acc = fmaf(n23, __builtin_amdgcn_rcpf(d23), acc);
    acc += __shfl_xor(acc, 1, 64);
    myred[(NW - 1) * 36] = acc;
  }
  __syncthreads();
  // Transpose-reduce: word n's 32 partials; lane n sums j=0..15, lane n+32
  // sums j=16..31; xor-32 combines. Lanes with n>=30 are dummies.
  int n = lane & 31; if (n >= NW) n = 0;
  int half = lane >> 5;
  const float4* rp4 = (const float4*)&red[wave][n][half * 16];
  float4 s4 = rp4[0];
  #pragma unroll
  for (int j = 1; j < 4; ++j) {
    float4 vv = rp4[j];
    s4.x += vv.x; s4.y += vv.y; s4.z += vv.z; s4.w += vv.w;
  }
  float tot = (s4.x + s4.y) + (s4.z + s4.w);
  tot += __shfl_xor(tot, 32, 64);
  // |score| <= sum|q| ~ 16 -> exp safe in fp32; softmax needs no max-shift.
  float e = __expf(Qsum + tot);
  if (lane < NW) expa[(size_t)b * EXPA_LD + lane] = e;
}

// ---------------------------------------------------------------------------
// Softmax-over-batch denominators, stage 1: 128 blocks x 256 titles each.
// part[n][blk] = sum over block's titles of expa[b][n].
// ---------------------------------------------------------------------------
__global__ __launch_bounds__(256) void softmax_part(const float* __restrict__ expa,
                                                    float* __restrict__ part) {
  __shared__ float P[256][33];
  int tid = threadIdx.x;
  const float* row = expa + (size_t)(blockIdx.x * 256 + tid) * EXPA_LD;
  #pragma unroll
  for (int j = 0; j < 7; ++j) {
    float4 vv = *(const float4*)(row + j * 4);
    P[tid][j * 4] = vv.x; P[tid][j * 4 + 1] = vv.y;
    P[tid][j * 4 + 2] = vv.z; P[tid][j * 4 + 3] = vv.w;
  }
  P[tid][28] = row[28]; P[tid][29] = row[29];
  __syncthreads();
  int wave = tid >> 6, lane = tid & 63;
  for (int n = wave * 8; n < wave * 8 + 8 && n < NW; ++n) {
    float s = P[lane * 4][n] + P[lane * 4 + 1][n] + P[lane * 4 + 2][n] + P[lane * 4 + 3][n];
    #pragma unroll
    for (int off = 32; off > 0; off >>= 1) s += __shfl_down(s, off, 64);
    if (lane == 0) part[n * 128 + blockIdx.x] = s;
  }
}

// Stage 2: rinv[n] = 1 / sum_blk part[n][blk]
__global__ void softmax_fin(const float* __restrict__ part, float* __restrict__ rinv) {
  int n = blockIdx.x;          // 30
  int lane = threadIdx.x;      // 64
  float s = part[n * 128 + lane] + part[n * 128 + 64 + lane];
  #pragma unroll
  for (int off = 32; off > 0; off >>= 1) s += __shfl_down(s, off, 64);
  if (lane == 0) rinv[n] = 1.0f / s;
}

// ---------------------------------------------------------------------------
// U[b, k*300+i] = sum_m alpha[b, m-k+1] * emb[tok[b,m], i]  -> bf16, stride 928
// Salpha[b] = sum_n alpha[b,n].  alpha = expa * rinv.
// R9: TWO titles per 320-thread block (stride 160; 300/320 lanes active vs
// 150/192) -> 82K waves instead of 98K for identical bytes/math.
// Prefetch-all-30 per title kept (R5-proven).
// ---------------------------------------------------------------------------
__global__ __launch_bounds__(320) void build_U(
    const int* __restrict__ tok, const unsigned short* __restrict__ embb,
    const float* __restrict__ expa, const float* __restrict__ rinv,
    unsigned short* __restrict__ U, float* __restrict__ Salpha) {
  int tid = threadIdx.x;
  int sub = tid >= 160 ? 1 : 0;
  int local = tid - sub * 160;
  int b = blockIdx.x * 2 + sub;
  __shared__ float alpha[2][NW];
  __shared__ int ltok[2][NW];
  if (local < NW) {
    ltok[sub][local] = tok[b * NW + local];
    alpha[sub][local] = expa[(size_t)b * EXPA_LD + local] * rinv[local];
  }
  __syncthreads();
  if (local == 0) {
    float s = 0.f;
    #pragma unroll
    for (int n = 0; n < NW; ++n) s += alpha[sub][n];
    Salpha[b] = s;
  }
  unsigned short* Ub = U + (size_t)b * U_LD;
  if (local < 150) {
    // Issue all 30 gathers (independent, fully unrolled -> 30 loads in flight)
    unsigned int uv[NW];
    #pragma unroll
    for (int m = 0; m < NW; ++m)
      uv[m] = *(const unsigned int*)(embb + (size_t)ltok[sub][m] * EMB_LD + 2 * local);
    // Broadcast alphas to registers (uniform ds_read, no conflicts)
    float al[NW];
    #pragma unroll
    for (int m = 0; m < NW; ++m) al[m] = alpha[sub][m];

    float a0 = 0.f, a1 = 0.f, a2 = 0.f;   // col x = 2*local
    float b0 = 0.f, b1 = 0.f, b2 = 0.f;   // col y = 2*local+1
    #pragma unroll
    for (int m = 0; m < NW; ++m) {
      float w0 = (m + 1 < NW) ? al[m + 1] : 0.f;
      float w1 = al[m];
      float w2 = (m >= 1) ? al[m - 1] : 0.f;
      float x = blo(uv[m]), y = bhi(uv[m]);
      a0 = fmaf(w0, x, a0); b0 = fmaf(w0, y, b0);
      a1 = fmaf(w1, x, a1); b1 = fmaf(w1, y, b1);
      a2 = fmaf(w2, x, a2); b2 = fmaf(w2, y, b2);
    }
    *(unsigned int*)(Ub + 2 * local)       = pack2bf(a0, b0);
    *(unsigned int*)(Ub + 300 + 2 * local) = pack2bf(a1, b1);
    *(unsigned int*)(Ub + 600 + 2 * local) = pack2bf(a2, b2);
  } else if (local < 157) {
    // zero pad 900..927: 7 threads x 4 shorts (uint2, 8B-aligned)
    uint2 z; z.x = 0u; z.y = 0u;
    *(uint2*)(Ub + 900 + 4 * (local - 150)) = z;
  }
}

// ---------------------------------------------------------------------------
extern "C" void kernel_launch(void* const* d_in, const int* in_sizes, int n_in,
                              void* d_out, int out_size, void* d_ws, size_t ws_size,
                              hipStream_t stream) {
  const int*   tok    = (const int*)d_in[0];
  const float* emb    = (const float*)d_in[1];
  const float* conv_w = (const float*)d_in[2];
  const float* conv_b = (const float*)d_in[3];
  const float* v      = (const float*)d_in[4];
  const float* vb     = (const float*)d_in[5];
  const float* q      = (const float*)d_in[6];
  float* out = (float*)d_out;

  // Workspace layout (byte offsets). Total ~87.8 MB.
  char* wb = (char*)d_ws;
  float* bias2           = (float*)(wb + 0);          // 200 f32
  float* rinv            = (float*)(wb + 4096);       // 30 f32
  float* part            = (float*)(wb + 8192);       // 30*128 f32 -> 23552
  float* q2s             = (float*)(wb + 23552);      // 200 f32
  float* qsum            = (float*)(wb + 24448);      // 1 f32
  float* Salpha          = (float*)(wb + 24576);      // 32768 f32 -> 155648
  float* expa            = (float*)(wb + 155648);     // 32768*32 f32 -> 4349952
  unsigned short* embb   = (unsigned short*)(wb + 5070848);   // 20.48MB -> 25550848
  unsigned short* MtT    = (unsigned short*)(wb + 25550848);  // 409600 -> 25960448
  unsigned short* WcT    = (unsigned short*)(wb + 25960448);  // 950272 -> 26910720
  unsigned short* big    = (unsigned short*)(wb + 26910720);  // E3 u8 (20.5MB) / U (60.8MB)
  unsigned char* E3 = (unsigned char*)big;
  unsigned short* U = big;   // E3 dead after scores_kernel

  // 1. Prep
  hipLaunchKernelGGL(prep_MtT_bias, dim3(642), dim3(320), 0, stream,
                     conv_w, conv_b, v, vb, q, MtT, bias2, q2s, qsum);
  hipLaunchKernelGGL(prep_WcT, dim3(WCT_ROWS), dim3(256), 0, stream, conv_w, WcT);
  hipLaunchKernelGGL(prep_emb_bf16, dim3((VOCAB * EMB_LD) / 256), dim3(256), 0, stream,
                     emb, embb);
  // 2. E3[32000,640]u8 = quant(embb @ MtT^T)+128, bias2 folded into cols [200,400)
  hipLaunchKernelGGL((gemm_mfma<1>), dim3(E3_LDB / 128, VOCAB / 128), dim3(256), 0, stream,
                     embb, EMB_LD, MtT, EMB_LD, (void*)E3, E3_LDB, E3_LDB, EMB_LD,
                     (const float*)nullptr, (const float*)nullptr, bias2);
  // 3. exp(scores) -> expa[b][n]  (rolling-window uint8 gather, LDS reduce)
  hipLaunchKernelGGL(scores_kernel, dim3(BT / 4), dim3(256), 0, stream,
                     tok, E3, q2s, qsum, expa);
  // 4. Softmax denominators (2-stage, deterministic)
  hipLaunchKernelGGL(softmax_part, dim3(128), dim3(256), 0, stream, expa, part);
  hipLaunchKernelGGL(softmax_fin, dim3(NW), dim3(64), 0, stream, part, rinv);
  // 5. U[32768,928]bf16 + Salpha  (2 titles per block)
  hipLaunchKernelGGL(build_U, dim3(BT / 2), dim3(320), 0, stream,
                     tok, embb, expa, rinv, U, Salpha);
  // 6. out[32768,400]f32 = U @ WcT^T + Salpha ⊗ conv_b
  hipLaunchKernelGGL((gemm_mfma<0>), dim3(WCT_ROWS / 128, BT / 128), dim3(256), 0, stream,
                     U, U_LD, WcT, U_LD, (void*)out, CH, CH, U_LD,
                     Salpha, conv_b, (const float*)nullptr);
}